// Round 1
// baseline (6268.169 us; speedup 1.0000x reference)
//
#include <hip/hip_runtime.h>

#define NN 20000
#define NE 320000
#define NH 64
#define NR 32

__device__ __forceinline__ float silu_f(float x) { return x / (1.0f + __expf(-x)); }

// ---------------- K1: node decompose + mix (lin_w[0..2]) -> Tm[N][64][9] ----------------
__global__ __launch_bounds__(256) void k1_node_mix(
    const float* __restrict__ X, const float* __restrict__ lw,
    float* __restrict__ Tm, int nnodes)
{
    __shared__ float xs[4 * 576];
    __shared__ float inc[4][64][12];
    const int tid = threadIdx.x;
    const int n0 = blockIdx.x * 4;
    if (n0 >= nnodes) return;

    const float4* s4 = (const float4*)(X + (size_t)n0 * 576);
    float4* x4 = (float4*)xs;
    for (int i = tid; i < 576; i += 256) x4[i] = s4[i];
    __syncthreads();

    const int sub = tid >> 6, lane = tid & 63;
    {
        const float* x = xs + sub * 576 + lane * 9;
        float v[9];
#pragma unroll
        for (int i = 0; i < 9; i++) v[i] = x[i];
        float tn = 0.f;
#pragma unroll
        for (int i = 0; i < 9; i++) tn = fmaf(v[i], v[i], tn);
        float inv = 1.0f / (tn + 1.0f);
#pragma unroll
        for (int i = 0; i < 9; i++) v[i] *= inv;
        float lam = (v[0] + v[4] + v[8]) * (1.0f / 3.0f);
        float* o = inc[sub][lane];
        o[0] = lam;
        o[1] = (v[1] - v[3]) * 0.5f;
        o[2] = (v[2] - v[6]) * 0.5f;
        o[3] = (v[5] - v[7]) * 0.5f;
        o[4] = v[0] - lam;
        o[5] = (v[1] + v[3]) * 0.5f;
        o[6] = (v[2] + v[6]) * 0.5f;
        o[7] = v[4] - lam;
        o[8] = (v[5] + v[7]) * 0.5f;
    }
    __syncthreads();

    const int g = lane;
    const float* W0 = lw + 0 * 4096 + g * 64;
    const float* W1 = lw + 1 * 4096 + g * 64;
    const float* W2 = lw + 2 * 4096 + g * 64;
    float acc[9];
#pragma unroll
    for (int i = 0; i < 9; i++) acc[i] = 0.f;
#pragma unroll 4
    for (int h = 0; h < 64; ++h) {
        float w0 = W0[h], w1v = W1[h], w2v = W2[h];
        const float* ic = inc[sub][h];
        acc[0] = fmaf(w0, ic[0], acc[0]);
        acc[1] = fmaf(w1v, ic[1], acc[1]);
        acc[2] = fmaf(w1v, ic[2], acc[2]);
        acc[3] = fmaf(w1v, ic[3], acc[3]);
        acc[4] = fmaf(w2v, ic[4], acc[4]);
        acc[5] = fmaf(w2v, ic[5], acc[5]);
        acc[6] = fmaf(w2v, ic[6], acc[6]);
        acc[7] = fmaf(w2v, ic[7], acc[7]);
        acc[8] = fmaf(w2v, ic[8], acc[8]);
    }
    float* outp = Tm + ((size_t)(n0 + sub) * 64 + g) * 9;
#pragma unroll
    for (int i = 0; i < 9; i++) outp[i] = acc[i];
}

// ---------------- K2: fused edge MLP + gather/scatter message ----------------
__global__ __launch_bounds__(256) void k2_edge(
    const float* __restrict__ ea, const float* __restrict__ dist,
    const int* __restrict__ eidx,
    const float* __restrict__ w1, const float* __restrict__ b1,
    const float* __restrict__ w2, const float* __restrict__ b2,
    const float* __restrict__ w3, const float* __restrict__ b3,
    const float* __restrict__ Tm, float* __restrict__ M, int nedges)
{
    __shared__ float act[4][2048];
    const int wid = threadIdx.x >> 6, lane = threadIdx.x & 63;
    const int e0 = (blockIdx.x * 4 + wid) * 16;
    if (e0 >= nedges) return;
    float* A = act[wid];

    // stage edge_attr [16][32] into LDS
    {
        const float4* s4 = (const float4*)(ea + (size_t)e0 * NR);
        float4* d4 = (float4*)A;
        d4[lane * 2 + 0] = s4[lane * 2 + 0];
        d4[lane * 2 + 1] = s4[lane * 2 + 1];
    }

    // ---- layer 1: [16][32] @ w1[64][32]^T -> h1[16][64] ----
    float wrow[32];
    {
        const float4* wr = (const float4*)(w1 + lane * NR);
#pragma unroll
        for (int i = 0; i < 8; i++) ((float4*)wrow)[i] = wr[i];
    }
    float acc1[16];
    {
        float bb = b1[lane];
#pragma unroll
        for (int e = 0; e < 16; e++) acc1[e] = bb;
    }
#pragma unroll
    for (int r = 0; r < 32; r += 4) {
#pragma unroll
        for (int e = 0; e < 16; e++) {
            float4 v = *(const float4*)(A + e * 32 + r);
            acc1[e] = fmaf(v.x, wrow[r + 0], acc1[e]);
            acc1[e] = fmaf(v.y, wrow[r + 1], acc1[e]);
            acc1[e] = fmaf(v.z, wrow[r + 2], acc1[e]);
            acc1[e] = fmaf(v.w, wrow[r + 3], acc1[e]);
        }
    }
#pragma unroll
    for (int e = 0; e < 16; e++) A[e * 64 + lane] = silu_f(acc1[e]);

    // ---- layer 2: h1[16][64] @ w2[128][64]^T -> h2[16][128] ----
    float acc2[32];
    {
        float b2a = b2[lane], b2b = b2[64 + lane];
#pragma unroll
        for (int e = 0; e < 16; e++) { acc2[e] = b2a; acc2[16 + e] = b2b; }
    }
    {
        const float* w2a = w2 + (size_t)lane * 64;
        const float* w2b = w2 + (size_t)(64 + lane) * 64;
#pragma unroll
        for (int k = 0; k < 64; k += 4) {
            float4 wa = *(const float4*)(w2a + k);
            float4 wb = *(const float4*)(w2b + k);
#pragma unroll
            for (int e = 0; e < 16; e++) {
                float4 v = *(const float4*)(A + e * 64 + k);
                float s1 = acc2[e], s2 = acc2[16 + e];
                s1 = fmaf(v.x, wa.x, s1); s1 = fmaf(v.y, wa.y, s1);
                s1 = fmaf(v.z, wa.z, s1); s1 = fmaf(v.w, wa.w, s1);
                s2 = fmaf(v.x, wb.x, s2); s2 = fmaf(v.y, wb.y, s2);
                s2 = fmaf(v.z, wb.z, s2); s2 = fmaf(v.w, wb.w, s2);
                acc2[e] = s1; acc2[16 + e] = s2;
            }
        }
    }
#pragma unroll
    for (int e = 0; e < 16; e++) {
        A[e * 128 + lane] = silu_f(acc2[e]);
        A[e * 128 + 64 + lane] = silu_f(acc2[16 + e]);
    }

    // ---- layer 3: h2[16][128] @ w3[192][128]^T -> ef[16][64][3] ----
    float acc3[48];
    {
        float ba = b3[lane * 3 + 0], bb = b3[lane * 3 + 1], bc = b3[lane * 3 + 2];
#pragma unroll
        for (int e = 0; e < 16; e++) {
            acc3[e * 3 + 0] = ba; acc3[e * 3 + 1] = bb; acc3[e * 3 + 2] = bc;
        }
    }
    {
        const float* w3a = w3 + (size_t)(lane * 3 + 0) * 128;
        const float* w3b = w3 + (size_t)(lane * 3 + 1) * 128;
        const float* w3c = w3 + (size_t)(lane * 3 + 2) * 128;
#pragma unroll 2
        for (int k = 0; k < 128; k += 4) {
            float4 wa = *(const float4*)(w3a + k);
            float4 wb = *(const float4*)(w3b + k);
            float4 wc = *(const float4*)(w3c + k);
#pragma unroll
            for (int e = 0; e < 16; e++) {
                float4 v = *(const float4*)(A + e * 128 + k);
                float sa = acc3[e * 3 + 0], sb = acc3[e * 3 + 1], sc = acc3[e * 3 + 2];
                sa = fmaf(v.x, wa.x, sa); sa = fmaf(v.y, wa.y, sa);
                sa = fmaf(v.z, wa.z, sa); sa = fmaf(v.w, wa.w, sa);
                sb = fmaf(v.x, wb.x, sb); sb = fmaf(v.y, wb.y, sb);
                sb = fmaf(v.z, wb.z, sb); sb = fmaf(v.w, wb.w, sb);
                sc = fmaf(v.x, wc.x, sc); sc = fmaf(v.y, wc.y, sc);
                sc = fmaf(v.z, wc.z, sc); sc = fmaf(v.w, wc.w, sc);
                acc3[e * 3 + 0] = sa; acc3[e * 3 + 1] = sb; acc3[e * 3 + 2] = sc;
            }
        }
    }

    // ---- epilogue: cutoff scale, gather Tm[col], scatter-add into M[row] ----
#pragma unroll 1
    for (int e = 0; e < 16; e++) {
        int ge = e0 + e;
        float d = dist[ge];
        float Cf = (d < 5.0f) ? 0.5f * (__cosf(d * 0.62831853071795864f) + 1.0f) : 0.0f;
        float f0 = acc3[e * 3 + 0] * Cf;
        float f1 = acc3[e * 3 + 1] * Cf;
        float f2 = acc3[e * 3 + 2] * Cf;
        int rn = eidx[ge];
        int cn = eidx[nedges + ge];
        const float* t = Tm + ((size_t)cn * 64 + lane) * 9;
        float* m = M + ((size_t)rn * 64 + lane) * 9;
        atomicAdd(m + 0, f0 * t[0]);
        atomicAdd(m + 1, f1 * t[1]);
        atomicAdd(m + 2, f1 * t[2]);
        atomicAdd(m + 3, f1 * t[3]);
        atomicAdd(m + 4, f2 * t[4]);
        atomicAdd(m + 5, f2 * t[5]);
        atomicAdd(m + 6, f2 * t[6]);
        atomicAdd(m + 7, f2 * t[7]);
        atomicAdd(m + 8, f2 * t[8]);
    }
}

// ---------------- K3: prod = M@Y + Y@M, decompose, /norm (in place into M) ----------------
__global__ __launch_bounds__(256) void k3_prod(
    const float* __restrict__ Tm, float* __restrict__ M, int nh)
{
    int i = blockIdx.x * 256 + threadIdx.x;
    if (i >= nh) return;
    float y[9], m[9];
    const float* tp = Tm + (size_t)i * 9;
    float* mp = M + (size_t)i * 9;
#pragma unroll
    for (int k = 0; k < 9; k++) { y[k] = tp[k]; m[k] = mp[k]; }
    float Y[9], Mm[9];
    Y[0] = y[0] + y[4]; Y[1] = y[1] + y[5]; Y[2] = y[2] + y[6];
    Y[3] = -y[1] + y[5]; Y[4] = y[0] + y[7]; Y[5] = y[3] + y[8];
    Y[6] = -y[2] + y[6]; Y[7] = -y[3] + y[8]; Y[8] = y[0] - y[4] - y[7];
    Mm[0] = m[0] + m[4]; Mm[1] = m[1] + m[5]; Mm[2] = m[2] + m[6];
    Mm[3] = -m[1] + m[5]; Mm[4] = m[0] + m[7]; Mm[5] = m[3] + m[8];
    Mm[6] = -m[2] + m[6]; Mm[7] = -m[3] + m[8]; Mm[8] = m[0] - m[4] - m[7];
    float P[9];
#pragma unroll
    for (int a = 0; a < 3; a++)
#pragma unroll
        for (int b = 0; b < 3; b++) {
            float s = 0.f;
#pragma unroll
            for (int c = 0; c < 3; c++) {
                s = fmaf(Mm[a * 3 + c], Y[c * 3 + b], s);
                s = fmaf(Y[a * 3 + c], Mm[c * 3 + b], s);
            }
            P[a * 3 + b] = s;
        }
    float tn = 0.f;
#pragma unroll
    for (int k = 0; k < 9; k++) tn = fmaf(P[k], P[k], tn);
    float inv = 1.0f / (tn + 1.0f);
    float lam = (P[0] + P[4] + P[8]) * (1.0f / 3.0f);
    mp[0] = lam * inv;
    mp[1] = (P[1] - P[3]) * 0.5f * inv;
    mp[2] = (P[2] - P[6]) * 0.5f * inv;
    mp[3] = (P[5] - P[7]) * 0.5f * inv;
    mp[4] = (P[0] - lam) * inv;
    mp[5] = (P[1] + P[3]) * 0.5f * inv;
    mp[6] = (P[2] + P[6]) * 0.5f * inv;
    mp[7] = (P[4] - lam) * inv;
    mp[8] = (P[5] + P[7]) * 0.5f * inv;
}

// ---------------- K4: mix (lin_w[3..5]) -> dX; out = Xn + dX + dX@dX ----------------
__global__ __launch_bounds__(256) void k4_final(
    const float* __restrict__ X, const float* __restrict__ lw,
    const float* __restrict__ pc, float* __restrict__ out, int nnodes)
{
    __shared__ float ps[4][64][12];
    const int tid = threadIdx.x;
    const int n0 = blockIdx.x * 4;
    if (n0 >= nnodes) return;
    const float* src = pc + (size_t)n0 * 576;
    for (int i = tid; i < 2304; i += 256) {
        int sub = i / 576; int rem = i - sub * 576;
        int hh = rem / 9; int c = rem - hh * 9;
        ps[sub][hh][c] = src[i];
    }
    __syncthreads();

    const int sub = tid >> 6, g = tid & 63;
    const float* W3 = lw + 3 * 4096 + g * 64;
    const float* W4 = lw + 4 * 4096 + g * 64;
    const float* W5 = lw + 5 * 4096 + g * 64;
    float acc[9];
#pragma unroll
    for (int i = 0; i < 9; i++) acc[i] = 0.f;
#pragma unroll 4
    for (int h = 0; h < 64; ++h) {
        float w3v = W3[h], w4v = W4[h], w5v = W5[h];
        const float* ic = ps[sub][h];
        acc[0] = fmaf(w3v, ic[0], acc[0]);
        acc[1] = fmaf(w4v, ic[1], acc[1]);
        acc[2] = fmaf(w4v, ic[2], acc[2]);
        acc[3] = fmaf(w4v, ic[3], acc[3]);
        acc[4] = fmaf(w5v, ic[4], acc[4]);
        acc[5] = fmaf(w5v, ic[5], acc[5]);
        acc[6] = fmaf(w5v, ic[6], acc[6]);
        acc[7] = fmaf(w5v, ic[7], acc[7]);
        acc[8] = fmaf(w5v, ic[8], acc[8]);
    }
    float D[9];
    D[0] = acc[0] + acc[4]; D[1] = acc[1] + acc[5]; D[2] = acc[2] + acc[6];
    D[3] = -acc[1] + acc[5]; D[4] = acc[0] + acc[7]; D[5] = acc[3] + acc[8];
    D[6] = -acc[2] + acc[6]; D[7] = -acc[3] + acc[8]; D[8] = acc[0] - acc[4] - acc[7];

    const float* xp = X + ((size_t)(n0 + sub) * 64 + g) * 9;
    float xv[9];
#pragma unroll
    for (int i = 0; i < 9; i++) xv[i] = xp[i];
    float tn = 0.f;
#pragma unroll
    for (int i = 0; i < 9; i++) tn = fmaf(xv[i], xv[i], tn);
    float inv = 1.0f / (tn + 1.0f);

    float* op = out + ((size_t)(n0 + sub) * 64 + g) * 9;
#pragma unroll
    for (int a = 0; a < 3; a++)
#pragma unroll
        for (int b = 0; b < 3; b++) {
            float dd = 0.f;
#pragma unroll
            for (int c = 0; c < 3; c++) dd = fmaf(D[a * 3 + c], D[c * 3 + b], dd);
            op[a * 3 + b] = xv[a * 3 + b] * inv + D[a * 3 + b] + dd;
        }
}

extern "C" void kernel_launch(void* const* d_in, const int* in_sizes, int n_in,
                              void* d_out, int out_size, void* d_ws, size_t ws_size,
                              hipStream_t stream)
{
    const float* X    = (const float*)d_in[0];
    const int*   eidx = (const int*)d_in[1];
    const float* dist = (const float*)d_in[2];
    const float* ea   = (const float*)d_in[3];
    const float* w1   = (const float*)d_in[4];
    const float* b1   = (const float*)d_in[5];
    const float* w2   = (const float*)d_in[6];
    const float* b2   = (const float*)d_in[7];
    const float* w3   = (const float*)d_in[8];
    const float* b3   = (const float*)d_in[9];
    const float* lw   = (const float*)d_in[10];
    float* outp = (float*)d_out;

    const int nnodes = in_sizes[0] / (64 * 9);   // 20000
    const int nedges = in_sizes[2];              // 320000
    const int nh = nnodes * 64;

    float* Tm = (float*)d_ws;
    float* M  = Tm + (size_t)nh * 9;

    hipMemsetAsync(M, 0, (size_t)nh * 9 * sizeof(float), stream);
    k1_node_mix<<<(nnodes + 3) / 4, 256, 0, stream>>>(X, lw, Tm, nnodes);
    k2_edge<<<(nedges + 63) / 64, 256, 0, stream>>>(ea, dist, eidx, w1, b1, w2, b2, w3, b3, Tm, M, nedges);
    k3_prod<<<(nh + 255) / 256, 256, 0, stream>>>(Tm, M, nh);
    k4_final<<<(nnodes + 3) / 4, 256, 0, stream>>>(X, lw, M, outp, nnodes);
}

// Round 2
// 1996.570 us; speedup vs baseline: 3.1395x; 3.1395x over previous
//
#include <hip/hip_runtime.h>

#define NR 32

__device__ __forceinline__ float silu_f(float x) { return x / (1.0f + __expf(-x)); }

// ---------------- CSR build ----------------
__global__ __launch_bounds__(256) void k_hist(
    const int* __restrict__ eidx, int* __restrict__ cnt, int nedges)
{
    int e = blockIdx.x * 256 + threadIdx.x;
    if (e < nedges) atomicAdd(&cnt[eidx[e]], 1);
}

__global__ __launch_bounds__(1024) void k_scan(
    int* __restrict__ cur_cnt, int* __restrict__ off, int n)
{
    __shared__ int sh[1024];
    __shared__ int carry;
    int tid = threadIdx.x;
    if (tid == 0) carry = 0;
    __syncthreads();
    for (int base = 0; base < n; base += 1024) {
        int i = base + tid;
        int v = (i < n) ? cur_cnt[i] : 0;
        sh[tid] = v;
        __syncthreads();
        for (int s = 1; s < 1024; s <<= 1) {
            int t = (tid >= s) ? sh[tid - s] : 0;
            __syncthreads();
            sh[tid] += t;
            __syncthreads();
        }
        int excl = carry + sh[tid] - v;
        if (i < n) { off[i] = excl; cur_cnt[i] = excl; }
        __syncthreads();
        if (tid == 0) carry += sh[1023];
        __syncthreads();
    }
    if (tid == 0) off[n] = carry;
}

__global__ __launch_bounds__(256) void k_scatter(
    const int* __restrict__ eidx, int* __restrict__ cur,
    int* __restrict__ perm, int nedges)
{
    int e = blockIdx.x * 256 + threadIdx.x;
    if (e < nedges) {
        int r = eidx[e];
        int pos = atomicAdd(&cur[r], 1);
        perm[pos] = e;
    }
}

// ---------------- K1: node decompose + mix (lin_w[0..2]) -> Tm[N][64][9] ----------------
__global__ __launch_bounds__(256) void k1_node_mix(
    const float* __restrict__ X, const float* __restrict__ lw,
    float* __restrict__ Tm, int nnodes)
{
    __shared__ float xs[4 * 576];
    __shared__ float inc[4][64][12];
    const int tid = threadIdx.x;
    const int n0 = blockIdx.x * 4;
    if (n0 >= nnodes) return;

    const float4* s4 = (const float4*)(X + (size_t)n0 * 576);
    float4* x4 = (float4*)xs;
    for (int i = tid; i < 576; i += 256) x4[i] = s4[i];
    __syncthreads();

    const int sub = tid >> 6, lane = tid & 63;
    {
        const float* x = xs + sub * 576 + lane * 9;
        float v[9];
#pragma unroll
        for (int i = 0; i < 9; i++) v[i] = x[i];
        float tn = 0.f;
#pragma unroll
        for (int i = 0; i < 9; i++) tn = fmaf(v[i], v[i], tn);
        float inv = 1.0f / (tn + 1.0f);
#pragma unroll
        for (int i = 0; i < 9; i++) v[i] *= inv;
        float lam = (v[0] + v[4] + v[8]) * (1.0f / 3.0f);
        float* o = inc[sub][lane];
        o[0] = lam;
        o[1] = (v[1] - v[3]) * 0.5f;
        o[2] = (v[2] - v[6]) * 0.5f;
        o[3] = (v[5] - v[7]) * 0.5f;
        o[4] = v[0] - lam;
        o[5] = (v[1] + v[3]) * 0.5f;
        o[6] = (v[2] + v[6]) * 0.5f;
        o[7] = v[4] - lam;
        o[8] = (v[5] + v[7]) * 0.5f;
    }
    __syncthreads();

    const int g = lane;
    const float* W0 = lw + 0 * 4096 + g * 64;
    const float* W1 = lw + 1 * 4096 + g * 64;
    const float* W2 = lw + 2 * 4096 + g * 64;
    float acc[9];
#pragma unroll
    for (int i = 0; i < 9; i++) acc[i] = 0.f;
#pragma unroll 4
    for (int h = 0; h < 64; ++h) {
        float w0 = W0[h], w1v = W1[h], w2v = W2[h];
        const float* ic = inc[sub][h];
        acc[0] = fmaf(w0, ic[0], acc[0]);
        acc[1] = fmaf(w1v, ic[1], acc[1]);
        acc[2] = fmaf(w1v, ic[2], acc[2]);
        acc[3] = fmaf(w1v, ic[3], acc[3]);
        acc[4] = fmaf(w2v, ic[4], acc[4]);
        acc[5] = fmaf(w2v, ic[5], acc[5]);
        acc[6] = fmaf(w2v, ic[6], acc[6]);
        acc[7] = fmaf(w2v, ic[7], acc[7]);
        acc[8] = fmaf(w2v, ic[8], acc[8]);
    }
    float* outp = Tm + ((size_t)(n0 + sub) * 64 + g) * 9;
#pragma unroll
    for (int i = 0; i < 9; i++) outp[i] = acc[i];
}

// ---------------- K2: CSR row-per-wave fused MLP + gather + register accumulate ----------------
__global__ __launch_bounds__(256) void k2_edge_csr(
    const float* __restrict__ ea, const float* __restrict__ dist,
    const int* __restrict__ eidx,
    const float* __restrict__ w1, const float* __restrict__ b1,
    const float* __restrict__ w2, const float* __restrict__ b2,
    const float* __restrict__ w3, const float* __restrict__ b3,
    const float* __restrict__ Tm,
    const int* __restrict__ off, const int* __restrict__ perm,
    float* __restrict__ M, int nrows, int nedges)
{
    __shared__ float act[4][2048];
    const int wid = threadIdx.x >> 6, lane = threadIdx.x & 63;
    const int r = blockIdx.x * 4 + wid;
    if (r >= nrows) return;
    float* A = act[wid];

    const int beg = off[r];
    const int deg = off[r + 1] - beg;

    float acc[9];
#pragma unroll
    for (int i = 0; i < 9; i++) acc[i] = 0.f;

    for (int c0 = 0; c0 < deg; c0 += 16) {
        const int cnt = min(16, deg - c0);

        // stage ea[16][32] into LDS (pad slots duplicate a valid edge)
#pragma unroll
        for (int it = 0; it < 2; it++) {
            int i = lane + it * 64;             // float4 index in [0,128)
            int slot = i >> 3;
            int idx = c0 + slot;
            int e = perm[beg + (idx < deg ? idx : 0)];
            ((float4*)A)[i] = ((const float4*)(ea + (size_t)e * NR))[i & 7];
        }

        // ---- layer 1: [16][32] @ w1[64][32]^T -> h1[16][64] ----
        float wrow[32];
        {
            const float4* wr = (const float4*)(w1 + lane * NR);
#pragma unroll
            for (int i = 0; i < 8; i++) ((float4*)wrow)[i] = wr[i];
        }
        float acc1[16];
        {
            float bb = b1[lane];
#pragma unroll
            for (int e = 0; e < 16; e++) acc1[e] = bb;
        }
#pragma unroll
        for (int rr = 0; rr < 32; rr += 4) {
#pragma unroll
            for (int e = 0; e < 16; e++) {
                float4 v = *(const float4*)(A + e * 32 + rr);
                acc1[e] = fmaf(v.x, wrow[rr + 0], acc1[e]);
                acc1[e] = fmaf(v.y, wrow[rr + 1], acc1[e]);
                acc1[e] = fmaf(v.z, wrow[rr + 2], acc1[e]);
                acc1[e] = fmaf(v.w, wrow[rr + 3], acc1[e]);
            }
        }
#pragma unroll
        for (int e = 0; e < 16; e++) A[e * 64 + lane] = silu_f(acc1[e]);

        // ---- layer 2: h1[16][64] @ w2[128][64]^T -> h2[16][128] ----
        float acc2[32];
        {
            float b2a = b2[lane], b2b = b2[64 + lane];
#pragma unroll
            for (int e = 0; e < 16; e++) { acc2[e] = b2a; acc2[16 + e] = b2b; }
        }
        {
            const float* w2a = w2 + (size_t)lane * 64;
            const float* w2b = w2 + (size_t)(64 + lane) * 64;
#pragma unroll
            for (int k = 0; k < 64; k += 4) {
                float4 wa = *(const float4*)(w2a + k);
                float4 wb = *(const float4*)(w2b + k);
#pragma unroll
                for (int e = 0; e < 16; e++) {
                    float4 v = *(const float4*)(A + e * 64 + k);
                    float s1 = acc2[e], s2 = acc2[16 + e];
                    s1 = fmaf(v.x, wa.x, s1); s1 = fmaf(v.y, wa.y, s1);
                    s1 = fmaf(v.z, wa.z, s1); s1 = fmaf(v.w, wa.w, s1);
                    s2 = fmaf(v.x, wb.x, s2); s2 = fmaf(v.y, wb.y, s2);
                    s2 = fmaf(v.z, wb.z, s2); s2 = fmaf(v.w, wb.w, s2);
                    acc2[e] = s1; acc2[16 + e] = s2;
                }
            }
        }
#pragma unroll
        for (int e = 0; e < 16; e++) {
            A[e * 128 + lane] = silu_f(acc2[e]);
            A[e * 128 + 64 + lane] = silu_f(acc2[16 + e]);
        }

        // ---- layer 3: h2[16][128] @ w3[192][128]^T -> ef[16][64][3] ----
        float acc3[48];
        {
            float ba = b3[lane * 3 + 0], bb = b3[lane * 3 + 1], bc = b3[lane * 3 + 2];
#pragma unroll
            for (int e = 0; e < 16; e++) {
                acc3[e * 3 + 0] = ba; acc3[e * 3 + 1] = bb; acc3[e * 3 + 2] = bc;
            }
        }
        {
            const float* w3a = w3 + (size_t)(lane * 3 + 0) * 128;
            const float* w3b = w3 + (size_t)(lane * 3 + 1) * 128;
            const float* w3c = w3 + (size_t)(lane * 3 + 2) * 128;
#pragma unroll 2
            for (int k = 0; k < 128; k += 4) {
                float4 wa = *(const float4*)(w3a + k);
                float4 wb = *(const float4*)(w3b + k);
                float4 wc = *(const float4*)(w3c + k);
#pragma unroll
                for (int e = 0; e < 16; e++) {
                    float4 v = *(const float4*)(A + e * 128 + k);
                    float sa = acc3[e * 3 + 0], sb = acc3[e * 3 + 1], sc = acc3[e * 3 + 2];
                    sa = fmaf(v.x, wa.x, sa); sa = fmaf(v.y, wa.y, sa);
                    sa = fmaf(v.z, wa.z, sa); sa = fmaf(v.w, wa.w, sa);
                    sb = fmaf(v.x, wb.x, sb); sb = fmaf(v.y, wb.y, sb);
                    sb = fmaf(v.z, wb.z, sb); sb = fmaf(v.w, wb.w, sb);
                    sc = fmaf(v.x, wc.x, sc); sc = fmaf(v.y, wc.y, sc);
                    sc = fmaf(v.z, wc.z, sc); sc = fmaf(v.w, wc.w, sc);
                    acc3[e * 3 + 0] = sa; acc3[e * 3 + 1] = sb; acc3[e * 3 + 2] = sc;
                }
            }
        }

        // ---- epilogue: cutoff scale, gather Tm[col], accumulate in registers ----
#pragma unroll 1
        for (int e = 0; e < cnt; e++) {
            int ge = perm[beg + c0 + e];
            float d = dist[ge];
            float Cf = (d < 5.0f) ? 0.5f * (__cosf(d * 0.62831853071795864f) + 1.0f) : 0.0f;
            float f0 = acc3[e * 3 + 0] * Cf;
            float f1 = acc3[e * 3 + 1] * Cf;
            float f2 = acc3[e * 3 + 2] * Cf;
            int cn = eidx[nedges + ge];
            const float* t = Tm + ((size_t)cn * 64 + lane) * 9;
            acc[0] = fmaf(f0, t[0], acc[0]);
            acc[1] = fmaf(f1, t[1], acc[1]);
            acc[2] = fmaf(f1, t[2], acc[2]);
            acc[3] = fmaf(f1, t[3], acc[3]);
            acc[4] = fmaf(f2, t[4], acc[4]);
            acc[5] = fmaf(f2, t[5], acc[5]);
            acc[6] = fmaf(f2, t[6], acc[6]);
            acc[7] = fmaf(f2, t[7], acc[7]);
            acc[8] = fmaf(f2, t[8], acc[8]);
        }
    }

    float* m = M + ((size_t)r * 64 + lane) * 9;
#pragma unroll
    for (int i = 0; i < 9; i++) m[i] = acc[i];
}

// ---------------- K3: prod = M@Y + Y@M, decompose, /norm (in place into M) ----------------
__global__ __launch_bounds__(256) void k3_prod(
    const float* __restrict__ Tm, float* __restrict__ M, int nh)
{
    int i = blockIdx.x * 256 + threadIdx.x;
    if (i >= nh) return;
    float y[9], m[9];
    const float* tp = Tm + (size_t)i * 9;
    float* mp = M + (size_t)i * 9;
#pragma unroll
    for (int k = 0; k < 9; k++) { y[k] = tp[k]; m[k] = mp[k]; }
    float Y[9], Mm[9];
    Y[0] = y[0] + y[4]; Y[1] = y[1] + y[5]; Y[2] = y[2] + y[6];
    Y[3] = -y[1] + y[5]; Y[4] = y[0] + y[7]; Y[5] = y[3] + y[8];
    Y[6] = -y[2] + y[6]; Y[7] = -y[3] + y[8]; Y[8] = y[0] - y[4] - y[7];
    Mm[0] = m[0] + m[4]; Mm[1] = m[1] + m[5]; Mm[2] = m[2] + m[6];
    Mm[3] = -m[1] + m[5]; Mm[4] = m[0] + m[7]; Mm[5] = m[3] + m[8];
    Mm[6] = -m[2] + m[6]; Mm[7] = -m[3] + m[8]; Mm[8] = m[0] - m[4] - m[7];
    float P[9];
#pragma unroll
    for (int a = 0; a < 3; a++)
#pragma unroll
        for (int b = 0; b < 3; b++) {
            float s = 0.f;
#pragma unroll
            for (int c = 0; c < 3; c++) {
                s = fmaf(Mm[a * 3 + c], Y[c * 3 + b], s);
                s = fmaf(Y[a * 3 + c], Mm[c * 3 + b], s);
            }
            P[a * 3 + b] = s;
        }
    float tn = 0.f;
#pragma unroll
    for (int k = 0; k < 9; k++) tn = fmaf(P[k], P[k], tn);
    float inv = 1.0f / (tn + 1.0f);
    float lam = (P[0] + P[4] + P[8]) * (1.0f / 3.0f);
    mp[0] = lam * inv;
    mp[1] = (P[1] - P[3]) * 0.5f * inv;
    mp[2] = (P[2] - P[6]) * 0.5f * inv;
    mp[3] = (P[5] - P[7]) * 0.5f * inv;
    mp[4] = (P[0] - lam) * inv;
    mp[5] = (P[1] + P[3]) * 0.5f * inv;
    mp[6] = (P[2] + P[6]) * 0.5f * inv;
    mp[7] = (P[4] - lam) * inv;
    mp[8] = (P[5] + P[7]) * 0.5f * inv;
}

// ---------------- K4: mix (lin_w[3..5]) -> dX; out = Xn + dX + dX@dX ----------------
__global__ __launch_bounds__(256) void k4_final(
    const float* __restrict__ X, const float* __restrict__ lw,
    const float* __restrict__ pc, float* __restrict__ out, int nnodes)
{
    __shared__ float ps[4][64][12];
    const int tid = threadIdx.x;
    const int n0 = blockIdx.x * 4;
    if (n0 >= nnodes) return;
    const float* src = pc + (size_t)n0 * 576;
    for (int i = tid; i < 2304; i += 256) {
        int sub = i / 576; int rem = i - sub * 576;
        int hh = rem / 9; int c = rem - hh * 9;
        ps[sub][hh][c] = src[i];
    }
    __syncthreads();

    const int sub = tid >> 6, g = tid & 63;
    const float* W3 = lw + 3 * 4096 + g * 64;
    const float* W4 = lw + 4 * 4096 + g * 64;
    const float* W5 = lw + 5 * 4096 + g * 64;
    float acc[9];
#pragma unroll
    for (int i = 0; i < 9; i++) acc[i] = 0.f;
#pragma unroll 4
    for (int h = 0; h < 64; ++h) {
        float w3v = W3[h], w4v = W4[h], w5v = W5[h];
        const float* ic = ps[sub][h];
        acc[0] = fmaf(w3v, ic[0], acc[0]);
        acc[1] = fmaf(w4v, ic[1], acc[1]);
        acc[2] = fmaf(w4v, ic[2], acc[2]);
        acc[3] = fmaf(w4v, ic[3], acc[3]);
        acc[4] = fmaf(w5v, ic[4], acc[4]);
        acc[5] = fmaf(w5v, ic[5], acc[5]);
        acc[6] = fmaf(w5v, ic[6], acc[6]);
        acc[7] = fmaf(w5v, ic[7], acc[7]);
        acc[8] = fmaf(w5v, ic[8], acc[8]);
    }
    float D[9];
    D[0] = acc[0] + acc[4]; D[1] = acc[1] + acc[5]; D[2] = acc[2] + acc[6];
    D[3] = -acc[1] + acc[5]; D[4] = acc[0] + acc[7]; D[5] = acc[3] + acc[8];
    D[6] = -acc[2] + acc[6]; D[7] = -acc[3] + acc[8]; D[8] = acc[0] - acc[4] - acc[7];

    const float* xp = X + ((size_t)(n0 + sub) * 64 + g) * 9;
    float xv[9];
#pragma unroll
    for (int i = 0; i < 9; i++) xv[i] = xp[i];
    float tn = 0.f;
#pragma unroll
    for (int i = 0; i < 9; i++) tn = fmaf(xv[i], xv[i], tn);
    float inv = 1.0f / (tn + 1.0f);

    float* op = out + ((size_t)(n0 + sub) * 64 + g) * 9;
#pragma unroll
    for (int a = 0; a < 3; a++)
#pragma unroll
        for (int b = 0; b < 3; b++) {
            float dd = 0.f;
#pragma unroll
            for (int c = 0; c < 3; c++) dd = fmaf(D[a * 3 + c], D[c * 3 + b], dd);
            op[a * 3 + b] = xv[a * 3 + b] * inv + D[a * 3 + b] + dd;
        }
}

extern "C" void kernel_launch(void* const* d_in, const int* in_sizes, int n_in,
                              void* d_out, int out_size, void* d_ws, size_t ws_size,
                              hipStream_t stream)
{
    const float* X    = (const float*)d_in[0];
    const int*   eidx = (const int*)d_in[1];
    const float* dist = (const float*)d_in[2];
    const float* ea   = (const float*)d_in[3];
    const float* w1   = (const float*)d_in[4];
    const float* b1   = (const float*)d_in[5];
    const float* w2   = (const float*)d_in[6];
    const float* b2   = (const float*)d_in[7];
    const float* w3   = (const float*)d_in[8];
    const float* b3   = (const float*)d_in[9];
    const float* lw   = (const float*)d_in[10];
    float* outp = (float*)d_out;

    const int nnodes = in_sizes[0] / (64 * 9);   // 20000
    const int nedges = in_sizes[2];              // 320000
    const int nh = nnodes * 64;

    float* Tm = (float*)d_ws;
    float* M  = Tm + (size_t)nh * 9;
    int* cur  = (int*)(M + (size_t)nh * 9);      // counts, then cursors
    int* off  = cur + nnodes;                    // nnodes+1
    int* perm = off + nnodes + 1;                // nedges

    // CSR build
    hipMemsetAsync(cur, 0, (size_t)nnodes * sizeof(int), stream);
    k_hist<<<(nedges + 255) / 256, 256, 0, stream>>>(eidx, cur, nedges);
    k_scan<<<1, 1024, 0, stream>>>(cur, off, nnodes);
    k_scatter<<<(nedges + 255) / 256, 256, 0, stream>>>(eidx, cur, perm, nedges);

    k1_node_mix<<<(nnodes + 3) / 4, 256, 0, stream>>>(X, lw, Tm, nnodes);
    k2_edge_csr<<<(nnodes + 3) / 4, 256, 0, stream>>>(ea, dist, eidx, w1, b1, w2, b2, w3, b3,
                                                      Tm, off, perm, M, nnodes, nedges);
    k3_prod<<<(nh + 255) / 256, 256, 0, stream>>>(Tm, M, nh);
    k4_final<<<(nnodes + 3) / 4, 256, 0, stream>>>(X, lw, M, outp, nnodes);
}

// Round 3
// 976.278 us; speedup vs baseline: 6.4205x; 2.0451x over previous
//
#include <hip/hip_runtime.h>
#include <hip/hip_fp16.h>

#define NR 32

__device__ __forceinline__ float silu_f(float x) { return x / (1.0f + __expf(-x)); }

// ---------------- CSR build ----------------
__global__ __launch_bounds__(256) void k_hist(
    const int* __restrict__ eidx, int* __restrict__ cnt, int nedges)
{
    int e = blockIdx.x * 256 + threadIdx.x;
    if (e < nedges) atomicAdd(&cnt[eidx[e]], 1);
}

__global__ __launch_bounds__(1024) void k_scan(
    int* __restrict__ cur_cnt, int* __restrict__ off, int n)
{
    __shared__ int sh[1024];
    __shared__ int carry;
    int tid = threadIdx.x;
    if (tid == 0) carry = 0;
    __syncthreads();
    for (int base = 0; base < n; base += 1024) {
        int i = base + tid;
        int v = (i < n) ? cur_cnt[i] : 0;
        sh[tid] = v;
        __syncthreads();
        for (int s = 1; s < 1024; s <<= 1) {
            int t = (tid >= s) ? sh[tid - s] : 0;
            __syncthreads();
            sh[tid] += t;
            __syncthreads();
        }
        int excl = carry + sh[tid] - v;
        if (i < n) { off[i] = excl; cur_cnt[i] = excl; }
        __syncthreads();
        if (tid == 0) carry += sh[1023];
        __syncthreads();
    }
    if (tid == 0) off[n] = carry;
}

__global__ __launch_bounds__(256) void k_scatter(
    const int* __restrict__ eidx, int* __restrict__ cur,
    int* __restrict__ perm, int* __restrict__ col_s, int nedges)
{
    int e = blockIdx.x * 256 + threadIdx.x;
    if (e < nedges) {
        int r = eidx[e];
        int pos = atomicAdd(&cur[r], 1);
        perm[pos] = e;
        col_s[pos] = eidx[nedges + e];
    }
}

// ---------------- K1: node decompose + mix (lin_w[0..2]) -> Tm[N][9][64] comp-major ----------------
__global__ __launch_bounds__(256) void k1_node_mix(
    const float* __restrict__ X, const float* __restrict__ lw,
    float* __restrict__ Tm, int nnodes)
{
    __shared__ float xs[4 * 576];
    __shared__ float inc[4][64][12];
    const int tid = threadIdx.x;
    const int n0 = blockIdx.x * 4;
    if (n0 >= nnodes) return;

    const float4* s4 = (const float4*)(X + (size_t)n0 * 576);
    float4* x4 = (float4*)xs;
    for (int i = tid; i < 576; i += 256) x4[i] = s4[i];
    __syncthreads();

    const int sub = tid >> 6, lane = tid & 63;
    {
        const float* x = xs + sub * 576 + lane * 9;
        float v[9];
#pragma unroll
        for (int i = 0; i < 9; i++) v[i] = x[i];
        float tn = 0.f;
#pragma unroll
        for (int i = 0; i < 9; i++) tn = fmaf(v[i], v[i], tn);
        float inv = 1.0f / (tn + 1.0f);
#pragma unroll
        for (int i = 0; i < 9; i++) v[i] *= inv;
        float lam = (v[0] + v[4] + v[8]) * (1.0f / 3.0f);
        float* o = inc[sub][lane];
        o[0] = lam;
        o[1] = (v[1] - v[3]) * 0.5f;
        o[2] = (v[2] - v[6]) * 0.5f;
        o[3] = (v[5] - v[7]) * 0.5f;
        o[4] = v[0] - lam;
        o[5] = (v[1] + v[3]) * 0.5f;
        o[6] = (v[2] + v[6]) * 0.5f;
        o[7] = v[4] - lam;
        o[8] = (v[5] + v[7]) * 0.5f;
    }
    __syncthreads();

    const int g = lane;
    const float* W0 = lw + 0 * 4096 + g * 64;
    const float* W1 = lw + 1 * 4096 + g * 64;
    const float* W2 = lw + 2 * 4096 + g * 64;
    float acc[9];
#pragma unroll
    for (int i = 0; i < 9; i++) acc[i] = 0.f;
#pragma unroll 4
    for (int h = 0; h < 64; ++h) {
        float w0 = W0[h], w1v = W1[h], w2v = W2[h];
        const float* ic = inc[sub][h];
        acc[0] = fmaf(w0, ic[0], acc[0]);
        acc[1] = fmaf(w1v, ic[1], acc[1]);
        acc[2] = fmaf(w1v, ic[2], acc[2]);
        acc[3] = fmaf(w1v, ic[3], acc[3]);
        acc[4] = fmaf(w2v, ic[4], acc[4]);
        acc[5] = fmaf(w2v, ic[5], acc[5]);
        acc[6] = fmaf(w2v, ic[6], acc[6]);
        acc[7] = fmaf(w2v, ic[7], acc[7]);
        acc[8] = fmaf(w2v, ic[8], acc[8]);
    }
    float* outp = Tm + (size_t)(n0 + sub) * 576 + g;
#pragma unroll
    for (int i = 0; i < 9; i++) outp[i * 64] = acc[i];
}

// ---------------- K2a: dense edge MLP over sorted positions -> ef_s[pos][3][64] fp16 ----------------
__global__ __launch_bounds__(256) void k2a_mlp(
    const float* __restrict__ ea, const float* __restrict__ dist,
    const int* __restrict__ perm,
    const float* __restrict__ w1, const float* __restrict__ b1,
    const float* __restrict__ w2, const float* __restrict__ b2,
    const float* __restrict__ w3, const float* __restrict__ b3,
    __half* __restrict__ efs, int nedges)
{
    __shared__ float act[4][2048];
    const int wid = threadIdx.x >> 6, lane = threadIdx.x & 63;
    const int p0 = (blockIdx.x * 4 + wid) * 16;
    if (p0 >= nedges) return;
    float* A = act[wid];

    // stage ea[16][32] into LDS via perm gather
#pragma unroll
    for (int it = 0; it < 2; it++) {
        int i = lane + it * 64;             // float4 index in [0,128)
        int slot = i >> 3;
        int idx = p0 + slot;
        int e = perm[idx < nedges ? idx : nedges - 1];
        ((float4*)A)[i] = ((const float4*)(ea + (size_t)e * NR))[i & 7];
    }

    // ---- layer 1: [16][32] @ w1[64][32]^T -> h1[16][64] ----
    float wrow[32];
    {
        const float4* wr = (const float4*)(w1 + lane * NR);
#pragma unroll
        for (int i = 0; i < 8; i++) ((float4*)wrow)[i] = wr[i];
    }
    float acc1[16];
    {
        float bb = b1[lane];
#pragma unroll
        for (int e = 0; e < 16; e++) acc1[e] = bb;
    }
#pragma unroll
    for (int rr = 0; rr < 32; rr += 4) {
#pragma unroll
        for (int e = 0; e < 16; e++) {
            float4 v = *(const float4*)(A + e * 32 + rr);
            acc1[e] = fmaf(v.x, wrow[rr + 0], acc1[e]);
            acc1[e] = fmaf(v.y, wrow[rr + 1], acc1[e]);
            acc1[e] = fmaf(v.z, wrow[rr + 2], acc1[e]);
            acc1[e] = fmaf(v.w, wrow[rr + 3], acc1[e]);
        }
    }
#pragma unroll
    for (int e = 0; e < 16; e++) A[e * 64 + lane] = silu_f(acc1[e]);

    // ---- layer 2: h1[16][64] @ w2[128][64]^T -> h2[16][128] ----
    float acc2[32];
    {
        float b2a = b2[lane], b2b = b2[64 + lane];
#pragma unroll
        for (int e = 0; e < 16; e++) { acc2[e] = b2a; acc2[16 + e] = b2b; }
    }
    {
        const float* w2a = w2 + (size_t)lane * 64;
        const float* w2b = w2 + (size_t)(64 + lane) * 64;
#pragma unroll
        for (int k = 0; k < 64; k += 4) {
            float4 wa = *(const float4*)(w2a + k);
            float4 wb = *(const float4*)(w2b + k);
#pragma unroll
            for (int e = 0; e < 16; e++) {
                float4 v = *(const float4*)(A + e * 64 + k);
                float s1 = acc2[e], s2 = acc2[16 + e];
                s1 = fmaf(v.x, wa.x, s1); s1 = fmaf(v.y, wa.y, s1);
                s1 = fmaf(v.z, wa.z, s1); s1 = fmaf(v.w, wa.w, s1);
                s2 = fmaf(v.x, wb.x, s2); s2 = fmaf(v.y, wb.y, s2);
                s2 = fmaf(v.z, wb.z, s2); s2 = fmaf(v.w, wb.w, s2);
                acc2[e] = s1; acc2[16 + e] = s2;
            }
        }
    }
#pragma unroll
    for (int e = 0; e < 16; e++) {
        A[e * 128 + lane] = silu_f(acc2[e]);
        A[e * 128 + 64 + lane] = silu_f(acc2[16 + e]);
    }

    // ---- layer 3: h2[16][128] @ w3[192][128]^T -> [16][64][3] ----
    float acc3[48];
    {
        float ba = b3[lane * 3 + 0], bb = b3[lane * 3 + 1], bc = b3[lane * 3 + 2];
#pragma unroll
        for (int e = 0; e < 16; e++) {
            acc3[e * 3 + 0] = ba; acc3[e * 3 + 1] = bb; acc3[e * 3 + 2] = bc;
        }
    }
    {
        const float* w3a = w3 + (size_t)(lane * 3 + 0) * 128;
        const float* w3b = w3 + (size_t)(lane * 3 + 1) * 128;
        const float* w3c = w3 + (size_t)(lane * 3 + 2) * 128;
#pragma unroll 2
        for (int k = 0; k < 128; k += 4) {
            float4 wa = *(const float4*)(w3a + k);
            float4 wb = *(const float4*)(w3b + k);
            float4 wc = *(const float4*)(w3c + k);
#pragma unroll
            for (int e = 0; e < 16; e++) {
                float4 v = *(const float4*)(A + e * 128 + k);
                float sa = acc3[e * 3 + 0], sb = acc3[e * 3 + 1], sc = acc3[e * 3 + 2];
                sa = fmaf(v.x, wa.x, sa); sa = fmaf(v.y, wa.y, sa);
                sa = fmaf(v.z, wa.z, sa); sa = fmaf(v.w, wa.w, sa);
                sb = fmaf(v.x, wb.x, sb); sb = fmaf(v.y, wb.y, sb);
                sb = fmaf(v.z, wb.z, sb); sb = fmaf(v.w, wb.w, sb);
                sc = fmaf(v.x, wc.x, sc); sc = fmaf(v.y, wc.y, sc);
                sc = fmaf(v.z, wc.z, sc); sc = fmaf(v.w, wc.w, sc);
                acc3[e * 3 + 0] = sa; acc3[e * 3 + 1] = sb; acc3[e * 3 + 2] = sc;
            }
        }
    }

    // ---- epilogue: cutoff scale, store fp16 [pos][3][64] ----
#pragma unroll 1
    for (int e = 0; e < 16; e++) {
        int idx = p0 + e;
        if (idx >= nedges) break;
        int ge = perm[idx];
        float d = dist[ge];
        float Cf = (d < 5.0f) ? 0.5f * (__cosf(d * 0.62831853071795864f) + 1.0f) : 0.0f;
        __half* o = efs + (size_t)idx * 192 + lane;
        o[0]   = __float2half(acc3[e * 3 + 0] * Cf);
        o[64]  = __float2half(acc3[e * 3 + 1] * Cf);
        o[128] = __float2half(acc3[e * 3 + 2] * Cf);
    }
}

// ---------------- K2b: row-per-wave accumulate + fused k3 -> out (pc, comp-major) ----------------
__global__ __launch_bounds__(256) void k2b_acc(
    const float* __restrict__ Tm, const __half* __restrict__ efs,
    const int* __restrict__ col_s, const int* __restrict__ off,
    float* __restrict__ out, int nrows)
{
    const int wid = threadIdx.x >> 6, lane = threadIdx.x & 63;
    const int r = blockIdx.x * 4 + wid;
    if (r >= nrows) return;
    const int beg = off[r];
    const int end = off[r + 1];

    float acc[9];
#pragma unroll
    for (int i = 0; i < 9; i++) acc[i] = 0.f;

#pragma unroll 2
    for (int p = beg; p < end; ++p) {
        int col = col_s[p];
        const float* t = Tm + (size_t)col * 576 + lane;
        const __half* f = efs + (size_t)p * 192 + lane;
        float f0 = __half2float(f[0]);
        float f1 = __half2float(f[64]);
        float f2 = __half2float(f[128]);
        acc[0] = fmaf(f0, t[0 * 64], acc[0]);
        acc[1] = fmaf(f1, t[1 * 64], acc[1]);
        acc[2] = fmaf(f1, t[2 * 64], acc[2]);
        acc[3] = fmaf(f1, t[3 * 64], acc[3]);
        acc[4] = fmaf(f2, t[4 * 64], acc[4]);
        acc[5] = fmaf(f2, t[5 * 64], acc[5]);
        acc[6] = fmaf(f2, t[6 * 64], acc[6]);
        acc[7] = fmaf(f2, t[7 * 64], acc[7]);
        acc[8] = fmaf(f2, t[8 * 64], acc[8]);
    }

    // fused k3: prod = M@Y + Y@M, decompose, /norm
    float y[9];
    {
        const float* tp = Tm + (size_t)r * 576 + lane;
#pragma unroll
        for (int k = 0; k < 9; k++) y[k] = tp[k * 64];
    }
    float Y[9], Mm[9];
    Y[0] = y[0] + y[4]; Y[1] = y[1] + y[5]; Y[2] = y[2] + y[6];
    Y[3] = -y[1] + y[5]; Y[4] = y[0] + y[7]; Y[5] = y[3] + y[8];
    Y[6] = -y[2] + y[6]; Y[7] = -y[3] + y[8]; Y[8] = y[0] - y[4] - y[7];
    Mm[0] = acc[0] + acc[4]; Mm[1] = acc[1] + acc[5]; Mm[2] = acc[2] + acc[6];
    Mm[3] = -acc[1] + acc[5]; Mm[4] = acc[0] + acc[7]; Mm[5] = acc[3] + acc[8];
    Mm[6] = -acc[2] + acc[6]; Mm[7] = -acc[3] + acc[8]; Mm[8] = acc[0] - acc[4] - acc[7];
    float P[9];
#pragma unroll
    for (int a = 0; a < 3; a++)
#pragma unroll
        for (int b = 0; b < 3; b++) {
            float s = 0.f;
#pragma unroll
            for (int c = 0; c < 3; c++) {
                s = fmaf(Mm[a * 3 + c], Y[c * 3 + b], s);
                s = fmaf(Y[a * 3 + c], Mm[c * 3 + b], s);
            }
            P[a * 3 + b] = s;
        }
    float tn = 0.f;
#pragma unroll
    for (int k = 0; k < 9; k++) tn = fmaf(P[k], P[k], tn);
    float inv = 1.0f / (tn + 1.0f);
    float lam = (P[0] + P[4] + P[8]) * (1.0f / 3.0f);

    float* mp = out + (size_t)r * 576 + lane;
    mp[0 * 64] = lam * inv;
    mp[1 * 64] = (P[1] - P[3]) * 0.5f * inv;
    mp[2 * 64] = (P[2] - P[6]) * 0.5f * inv;
    mp[3 * 64] = (P[5] - P[7]) * 0.5f * inv;
    mp[4 * 64] = (P[0] - lam) * inv;
    mp[5 * 64] = (P[1] + P[3]) * 0.5f * inv;
    mp[6 * 64] = (P[2] + P[6]) * 0.5f * inv;
    mp[7 * 64] = (P[4] - lam) * inv;
    mp[8 * 64] = (P[5] + P[7]) * 0.5f * inv;
}

// ---------------- K4: mix (lin_w[3..5]) -> dX; out = Xn + dX + dX@dX (in-place over pc) ----------------
__global__ __launch_bounds__(256) void k4_final(
    const float* __restrict__ X, const float* __restrict__ lw,
    float* __restrict__ out, int nnodes)
{
    __shared__ float ps[4][64][12];
    const int tid = threadIdx.x;
    const int n0 = blockIdx.x * 4;
    if (n0 >= nnodes) return;
    const float* src = out + (size_t)n0 * 576;   // pc, comp-major [node][9][64]
    for (int i = tid; i < 2304; i += 256) {
        int sub = i / 576; int rem = i - sub * 576;
        int c = rem >> 6; int hh = rem & 63;
        ps[sub][hh][c] = src[i];
    }
    __syncthreads();

    const int sub = tid >> 6, g = tid & 63;
    const float* W3 = lw + 3 * 4096 + g * 64;
    const float* W4 = lw + 4 * 4096 + g * 64;
    const float* W5 = lw + 5 * 4096 + g * 64;
    float acc[9];
#pragma unroll
    for (int i = 0; i < 9; i++) acc[i] = 0.f;
#pragma unroll 4
    for (int h = 0; h < 64; ++h) {
        float w3v = W3[h], w4v = W4[h], w5v = W5[h];
        const float* ic = ps[sub][h];
        acc[0] = fmaf(w3v, ic[0], acc[0]);
        acc[1] = fmaf(w4v, ic[1], acc[1]);
        acc[2] = fmaf(w4v, ic[2], acc[2]);
        acc[3] = fmaf(w4v, ic[3], acc[3]);
        acc[4] = fmaf(w5v, ic[4], acc[4]);
        acc[5] = fmaf(w5v, ic[5], acc[5]);
        acc[6] = fmaf(w5v, ic[6], acc[6]);
        acc[7] = fmaf(w5v, ic[7], acc[7]);
        acc[8] = fmaf(w5v, ic[8], acc[8]);
    }
    float D[9];
    D[0] = acc[0] + acc[4]; D[1] = acc[1] + acc[5]; D[2] = acc[2] + acc[6];
    D[3] = -acc[1] + acc[5]; D[4] = acc[0] + acc[7]; D[5] = acc[3] + acc[8];
    D[6] = -acc[2] + acc[6]; D[7] = -acc[3] + acc[8]; D[8] = acc[0] - acc[4] - acc[7];

    const float* xp = X + ((size_t)(n0 + sub) * 64 + g) * 9;
    float xv[9];
#pragma unroll
    for (int i = 0; i < 9; i++) xv[i] = xp[i];
    float tn = 0.f;
#pragma unroll
    for (int i = 0; i < 9; i++) tn = fmaf(xv[i], xv[i], tn);
    float inv = 1.0f / (tn + 1.0f);

    float* op = out + ((size_t)(n0 + sub) * 64 + g) * 9;   // final output, [N][64][3][3]
    float res[9];
#pragma unroll
    for (int a = 0; a < 3; a++)
#pragma unroll
        for (int b = 0; b < 3; b++) {
            float dd = 0.f;
#pragma unroll
            for (int c = 0; c < 3; c++) dd = fmaf(D[a * 3 + c], D[c * 3 + b], dd);
            res[a * 3 + b] = xv[a * 3 + b] * inv + D[a * 3 + b] + dd;
        }
    __syncthreads();   // all reads of pc staged before overwrite
#pragma unroll
    for (int i = 0; i < 9; i++) op[i] = res[i];
}

extern "C" void kernel_launch(void* const* d_in, const int* in_sizes, int n_in,
                              void* d_out, int out_size, void* d_ws, size_t ws_size,
                              hipStream_t stream)
{
    const float* X    = (const float*)d_in[0];
    const int*   eidx = (const int*)d_in[1];
    const float* dist = (const float*)d_in[2];
    const float* ea   = (const float*)d_in[3];
    const float* w1   = (const float*)d_in[4];
    const float* b1   = (const float*)d_in[5];
    const float* w2   = (const float*)d_in[6];
    const float* b2   = (const float*)d_in[7];
    const float* w3   = (const float*)d_in[8];
    const float* b3   = (const float*)d_in[9];
    const float* lw   = (const float*)d_in[10];
    float* outp = (float*)d_out;

    const int nnodes = in_sizes[0] / (64 * 9);   // 20000
    const int nedges = in_sizes[2];              // 320000

    float* Tm   = (float*)d_ws;                          // N*576 f32
    __half* efs = (__half*)(Tm + (size_t)nnodes * 576);  // E*192 f16
    int* cur    = (int*)(efs + (size_t)nedges * 192);
    int* off    = cur + nnodes;                          // nnodes+1
    int* perm   = off + nnodes + 1;                      // nedges
    int* col_s  = perm + nedges;                         // nedges

    // CSR build (edges sorted by destination row; col pre-gathered)
    hipMemsetAsync(cur, 0, (size_t)nnodes * sizeof(int), stream);
    k_hist<<<(nedges + 255) / 256, 256, 0, stream>>>(eidx, cur, nedges);
    k_scan<<<1, 1024, 0, stream>>>(cur, off, nnodes);
    k_scatter<<<(nedges + 255) / 256, 256, 0, stream>>>(eidx, cur, perm, col_s, nedges);

    k1_node_mix<<<(nnodes + 3) / 4, 256, 0, stream>>>(X, lw, Tm, nnodes);
    k2a_mlp<<<(nedges + 63) / 64, 256, 0, stream>>>(ea, dist, perm, w1, b1, w2, b2, w3, b3, efs, nedges);
    k2b_acc<<<(nnodes + 3) / 4, 256, 0, stream>>>(Tm, efs, col_s, off, outp, nnodes);
    k4_final<<<(nnodes + 3) / 4, 256, 0, stream>>>(X, lw, outp, nnodes);
}

// Round 5
// 602.659 us; speedup vs baseline: 10.4008x; 1.6200x over previous
//
#include <hip/hip_runtime.h>
#include <hip/hip_fp16.h>

#define NR 32

typedef __attribute__((ext_vector_type(8))) short bf8_t;   // 8 x bf16 (4 VGPR)
typedef __attribute__((ext_vector_type(4))) float f4_t;

__device__ __forceinline__ float silu_f(float x) { return x / (1.0f + __expf(-x)); }

__device__ __forceinline__ unsigned short f2bf(float x) {
    unsigned u = __float_as_uint(x);
    u += 0x7FFF + ((u >> 16) & 1);          // round-to-nearest-even
    return (unsigned short)(u >> 16);
}

// ---------------- CSR build ----------------
__global__ __launch_bounds__(256) void k_hist(
    const int* __restrict__ eidx, int* __restrict__ cnt, int nedges)
{
    int e = blockIdx.x * 256 + threadIdx.x;
    if (e < nedges) atomicAdd(&cnt[eidx[e]], 1);
}

__global__ __launch_bounds__(1024) void k_scan2(
    int* __restrict__ cnt, int* __restrict__ off, int n)
{
    __shared__ int wsum[16];
    __shared__ int wbase[16];
    const int tid = threadIdx.x;
    const int lane = tid & 63, wid = tid >> 6;
    const int per = (n + 1023) >> 10;
    const int base = tid * per;
    int s = 0;
    for (int i = 0; i < per; i++) {
        int idx = base + i;
        if (idx < n) s += cnt[idx];
    }
    int incl = s;
    for (int d = 1; d < 64; d <<= 1) {
        int t = __shfl_up(incl, d);
        if (lane >= d) incl += t;
    }
    if (lane == 63) wsum[wid] = incl;
    __syncthreads();
    if (wid == 0) {
        int v = (lane < 16) ? wsum[lane] : 0;
        int inc2 = v;
        for (int d = 1; d < 16; d <<= 1) {
            int t = __shfl_up(inc2, d);
            if (lane >= d) inc2 += t;
        }
        if (lane < 16) wbase[lane] = inc2 - v;
        if (lane == 15) off[n] = inc2;
    }
    __syncthreads();
    int run = wbase[wid] + incl - s;
    for (int i = 0; i < per; i++) {
        int idx = base + i;
        if (idx < n) {
            int v = cnt[idx];
            off[idx] = run;
            cnt[idx] = run;
            run += v;
        }
    }
}

__global__ __launch_bounds__(256) void k_scatter(
    const int* __restrict__ eidx, int* __restrict__ cur,
    int* __restrict__ perm, int* __restrict__ col_s, int nedges)
{
    int e = blockIdx.x * 256 + threadIdx.x;
    if (e < nedges) {
        int r = eidx[e];
        int pos = atomicAdd(&cur[r], 1);
        perm[pos] = e;
        col_s[pos] = eidx[nedges + e];
    }
}

// ---------------- K1: node decompose + mix (lin_w[0..2]) -> Tm[N][9][64] comp-major ----------------
__global__ __launch_bounds__(256) void k1_node_mix(
    const float* __restrict__ X, const float* __restrict__ lw,
    float* __restrict__ Tm, int nnodes)
{
    __shared__ float xs[4 * 576];
    __shared__ float inc[4][64][12];
    const int tid = threadIdx.x;
    const int n0 = blockIdx.x * 4;
    if (n0 >= nnodes) return;

    const float4* s4 = (const float4*)(X + (size_t)n0 * 576);
    float4* x4 = (float4*)xs;
    for (int i = tid; i < 576; i += 256) x4[i] = s4[i];
    __syncthreads();

    const int sub = tid >> 6, lane = tid & 63;
    {
        const float* x = xs + sub * 576 + lane * 9;
        float v[9];
#pragma unroll
        for (int i = 0; i < 9; i++) v[i] = x[i];
        float tn = 0.f;
#pragma unroll
        for (int i = 0; i < 9; i++) tn = fmaf(v[i], v[i], tn);
        float inv = 1.0f / (tn + 1.0f);
#pragma unroll
        for (int i = 0; i < 9; i++) v[i] *= inv;
        float lam = (v[0] + v[4] + v[8]) * (1.0f / 3.0f);
        float* o = inc[sub][lane];
        o[0] = lam;
        o[1] = (v[1] - v[3]) * 0.5f;
        o[2] = (v[2] - v[6]) * 0.5f;
        o[3] = (v[5] - v[7]) * 0.5f;
        o[4] = v[0] - lam;
        o[5] = (v[1] + v[3]) * 0.5f;
        o[6] = (v[2] + v[6]) * 0.5f;
        o[7] = v[4] - lam;
        o[8] = (v[5] + v[7]) * 0.5f;
    }
    __syncthreads();

    const int g = lane;
    const float* W0 = lw + 0 * 4096 + g * 64;
    const float* W1 = lw + 1 * 4096 + g * 64;
    const float* W2 = lw + 2 * 4096 + g * 64;
    float acc[9];
#pragma unroll
    for (int i = 0; i < 9; i++) acc[i] = 0.f;
#pragma unroll 4
    for (int h = 0; h < 64; ++h) {
        float w0 = W0[h], w1v = W1[h], w2v = W2[h];
        const float* ic = inc[sub][h];
        acc[0] = fmaf(w0, ic[0], acc[0]);
        acc[1] = fmaf(w1v, ic[1], acc[1]);
        acc[2] = fmaf(w1v, ic[2], acc[2]);
        acc[3] = fmaf(w1v, ic[3], acc[3]);
        acc[4] = fmaf(w2v, ic[4], acc[4]);
        acc[5] = fmaf(w2v, ic[5], acc[5]);
        acc[6] = fmaf(w2v, ic[6], acc[6]);
        acc[7] = fmaf(w2v, ic[7], acc[7]);
        acc[8] = fmaf(w2v, ic[8], acc[8]);
    }
    float* outp = Tm + (size_t)(n0 + sub) * 576 + g;
#pragma unroll
    for (int i = 0; i < 9; i++) outp[i * 64] = acc[i];
}

// ---------------- K2a: MFMA fused edge MLP -> efs[pos][192] fp16 (f = 3h+c) ----------------
// LDS map (bytes): w1 [0,4096) linear; w2 [4096,20480) swz; w3 [20480,69632) swz;
// per-wave act: h1 (2 KB bf16 [16][64]) + h2 (4 KB bf16 [16][128]) at 69632 + wid*6144.
#define LW1 0
#define LW2 4096
#define LW3 20480
#define LHB 69632

__global__ __launch_bounds__(512) void k2a_mfma(
    const float* __restrict__ ea, const float* __restrict__ dist,
    const int* __restrict__ perm,
    const float* __restrict__ w1, const float* __restrict__ b1,
    const float* __restrict__ w2, const float* __restrict__ b2,
    const float* __restrict__ w3, const float* __restrict__ b3,
    __half* __restrict__ efs, int nedges)
{
    __shared__ __align__(16) char smem[118784];
    const int tid = threadIdx.x;

    // ---- stage weights as bf16 (block-wide, once) ----
    for (int i = tid; i < 1024; i += 512) {            // w1: 64x32, linear rows (64 B row)
        unsigned lo = f2bf(w1[2 * i]), hi = f2bf(w1[2 * i + 1]);
        *(unsigned*)(smem + LW1 + i * 4) = lo | (hi << 16);
    }
    for (int i = tid; i < 4096; i += 512) {            // w2: 128x64, 128 B row, swz
        int row = i >> 5, pc = i & 31;
        int byte = (row * 128 + pc * 4) ^ ((row & 7) << 4);
        unsigned lo = f2bf(w2[2 * i]), hi = f2bf(w2[2 * i + 1]);
        *(unsigned*)(smem + LW2 + byte) = lo | (hi << 16);
    }
    for (int i = tid; i < 12288; i += 512) {           // w3: 192x128, 256 B row, swz
        int row = i >> 6, pc = i & 63;
        int byte = (row * 256 + pc * 4) ^ ((row & 7) << 4);
        unsigned lo = f2bf(w3[2 * i]), hi = f2bf(w3[2 * i + 1]);
        *(unsigned*)(smem + LW3 + byte) = lo | (hi << 16);
    }
    __syncthreads();

    const int wid = tid >> 6, lane = tid & 63;
    const int r = lane & 15, g = lane >> 4;
    char* h1b = smem + LHB + wid * 6144;
    char* h2b = h1b + 2048;
    const int eb = blockIdx.x * 512 + wid * 64;
    if (eb >= nedges) return;

    // held B-frags for w1 (K=32 fits one frag set)
    bf8_t bw1[4];
#pragma unroll
    for (int nt = 0; nt < 4; nt++)
        bw1[nt] = *(const bf8_t*)(smem + LW1 + (16 * nt + r) * 64 + g * 16);

    float b1v[4], b2v[8], b3v[12];
#pragma unroll
    for (int nt = 0; nt < 4; nt++)  b1v[nt] = b1[16 * nt + r];
#pragma unroll
    for (int nt = 0; nt < 8; nt++)  b2v[nt] = b2[16 * nt + r];
#pragma unroll
    for (int nt = 0; nt < 12; nt++) b3v[nt] = b3[16 * nt + r];

    for (int mt = 0; mt < 4; mt++) {
        int p = eb + mt * 16 + r;
        int pcl = min(p, nedges - 1);
        int e = perm[pcl];

        // A1 frag: ea[e][8g..8g+7] (row=r edge, k contiguous)
        const float* ar = ea + (size_t)e * NR + 8 * g;
        float4 v0 = *(const float4*)(ar);
        float4 v1 = *(const float4*)(ar + 4);
        bf8_t a1;
        a1[0] = f2bf(v0.x); a1[1] = f2bf(v0.y); a1[2] = f2bf(v0.z); a1[3] = f2bf(v0.w);
        a1[4] = f2bf(v1.x); a1[5] = f2bf(v1.y); a1[6] = f2bf(v1.z); a1[7] = f2bf(v1.w);

        float d = dist[e];
        float cf = (d < 5.0f) ? 0.5f * (__cosf(d * 0.62831853071795864f) + 1.0f) : 0.0f;
        float cfr[4];
#pragma unroll
        for (int j = 0; j < 4; j++) cfr[j] = __shfl(cf, 4 * g + j);   // cf of C-row 4g+j

        // ---- L1: h1[16][64] ----
#pragma unroll
        for (int nt = 0; nt < 4; nt++) {
            f4_t c = { b1v[nt], b1v[nt], b1v[nt], b1v[nt] };
            c = __builtin_amdgcn_mfma_f32_16x16x32_bf16(a1, bw1[nt], c, 0, 0, 0);
#pragma unroll
            for (int j = 0; j < 4; j++) {
                int row = 4 * g + j, col = 16 * nt + r;
                int byte = (row * 128 + col * 2) ^ ((row & 7) << 4);
                *(unsigned short*)(h1b + byte) = f2bf(silu_f(c[j]));
            }
        }

        // ---- L2: h2[16][128] ----
        bf8_t a2[2];
#pragma unroll
        for (int kt = 0; kt < 2; kt++)
            a2[kt] = *(const bf8_t*)(h1b + ((r * 128 + kt * 64 + g * 16) ^ ((r & 7) << 4)));
#pragma unroll
        for (int nt = 0; nt < 8; nt++) {
            int c0 = 16 * nt + r;
            f4_t c = { b2v[nt], b2v[nt], b2v[nt], b2v[nt] };
#pragma unroll
            for (int kt = 0; kt < 2; kt++) {
                bf8_t bw = *(const bf8_t*)(smem + LW2 + ((c0 * 128 + kt * 64 + g * 16) ^ ((c0 & 7) << 4)));
                c = __builtin_amdgcn_mfma_f32_16x16x32_bf16(a2[kt], bw, c, 0, 0, 0);
            }
#pragma unroll
            for (int j = 0; j < 4; j++) {
                int row = 4 * g + j;
                int byte = (row * 256 + (16 * nt + r) * 2) ^ ((row & 7) << 4);
                *(unsigned short*)(h2b + byte) = f2bf(silu_f(c[j]));
            }
        }

        // ---- L3: [16][192] + cutoff epilogue ----
        bf8_t a3[4];
#pragma unroll
        for (int kt = 0; kt < 4; kt++)
            a3[kt] = *(const bf8_t*)(h2b + ((r * 256 + kt * 64 + g * 16) ^ ((r & 7) << 4)));
#pragma unroll
        for (int nt = 0; nt < 12; nt++) {
            int c0 = 16 * nt + r;
            f4_t c = { b3v[nt], b3v[nt], b3v[nt], b3v[nt] };
#pragma unroll
            for (int kt = 0; kt < 4; kt++) {
                bf8_t bw = *(const bf8_t*)(smem + LW3 + ((c0 * 256 + kt * 64 + g * 16) ^ ((c0 & 7) << 4)));
                c = __builtin_amdgcn_mfma_f32_16x16x32_bf16(a3[kt], bw, c, 0, 0, 0);
            }
#pragma unroll
            for (int j = 0; j < 4; j++) {
                int prow = eb + mt * 16 + 4 * g + j;
                if (prow < nedges)
                    efs[(size_t)prow * 192 + 16 * nt + r] = __float2half(c[j] * cfr[j]);
            }
        }
    }
}

// ---------------- K2b: row-per-wave accumulate + fused k3 -> out (pc, comp-major) ----------------
__global__ __launch_bounds__(256) void k2b_acc(
    const float* __restrict__ Tm, const __half* __restrict__ efs,
    const int* __restrict__ col_s, const int* __restrict__ off,
    float* __restrict__ out, int nrows)
{
    const int wid = threadIdx.x >> 6, lane = threadIdx.x & 63;
    const int r = blockIdx.x * 4 + wid;
    if (r >= nrows) return;
    const int beg = off[r];
    const int end = off[r + 1];

    float acc[9];
#pragma unroll
    for (int i = 0; i < 9; i++) acc[i] = 0.f;

#pragma unroll 2
    for (int p = beg; p < end; ++p) {
        int col = col_s[p];
        const float* t = Tm + (size_t)col * 576 + lane;
        const __half* f = efs + (size_t)p * 192 + 3 * lane;
        float f0 = __half2float(f[0]);
        float f1 = __half2float(f[1]);
        float f2 = __half2float(f[2]);
        acc[0] = fmaf(f0, t[0 * 64], acc[0]);
        acc[1] = fmaf(f1, t[1 * 64], acc[1]);
        acc[2] = fmaf(f1, t[2 * 64], acc[2]);
        acc[3] = fmaf(f1, t[3 * 64], acc[3]);
        acc[4] = fmaf(f2, t[4 * 64], acc[4]);
        acc[5] = fmaf(f2, t[5 * 64], acc[5]);
        acc[6] = fmaf(f2, t[6 * 64], acc[6]);
        acc[7] = fmaf(f2, t[7 * 64], acc[7]);
        acc[8] = fmaf(f2, t[8 * 64], acc[8]);
    }

    // fused k3: prod = M@Y + Y@M, decompose, /norm
    float y[9];
    {
        const float* tp = Tm + (size_t)r * 576 + lane;
#pragma unroll
        for (int k = 0; k < 9; k++) y[k] = tp[k * 64];
    }
    float Y[9], Mm[9];
    Y[0] = y[0] + y[4]; Y[1] = y[1] + y[5]; Y[2] = y[2] + y[6];
    Y[3] = -y[1] + y[5]; Y[4] = y[0] + y[7]; Y[5] = y[3] + y[8];
    Y[6] = -y[2] + y[6]; Y[7] = -y[3] + y[8]; Y[8] = y[0] - y[4] - y[7];
    Mm[0] = acc[0] + acc[4]; Mm[1] = acc[1] + acc[5]; Mm[2] = acc[2] + acc[6];
    Mm[3] = -acc[1] + acc[5]; Mm[4] = acc[0] + acc[7]; Mm[5] = acc[3] + acc[8];
    Mm[6] = -acc[2] + acc[6]; Mm[7] = -acc[3] + acc[8]; Mm[8] = acc[0] - acc[4] - acc[7];
    float P[9];
#pragma unroll
    for (int a = 0; a < 3; a++)
#pragma unroll
        for (int b = 0; b < 3; b++) {
            float s = 0.f;
#pragma unroll
            for (int c = 0; c < 3; c++) {
                s = fmaf(Mm[a * 3 + c], Y[c * 3 + b], s);
                s = fmaf(Y[a * 3 + c], Mm[c * 3 + b], s);
            }
            P[a * 3 + b] = s;
        }
    float tn = 0.f;
#pragma unroll
    for (int k = 0; k < 9; k++) tn = fmaf(P[k], P[k], tn);
    float inv = 1.0f / (tn + 1.0f);
    float lam = (P[0] + P[4] + P[8]) * (1.0f / 3.0f);

    float* mp = out + (size_t)r * 576 + lane;
    mp[0 * 64] = lam * inv;
    mp[1 * 64] = (P[1] - P[3]) * 0.5f * inv;
    mp[2 * 64] = (P[2] - P[6]) * 0.5f * inv;
    mp[3 * 64] = (P[5] - P[7]) * 0.5f * inv;
    mp[4 * 64] = (P[0] - lam) * inv;
    mp[5 * 64] = (P[1] + P[3]) * 0.5f * inv;
    mp[6 * 64] = (P[2] + P[6]) * 0.5f * inv;
    mp[7 * 64] = (P[4] - lam) * inv;
    mp[8 * 64] = (P[5] + P[7]) * 0.5f * inv;
}

// ---------------- K4: mix (lin_w[3..5]) -> dX; out = Xn + dX + dX@dX (in-place over pc) ----------------
__global__ __launch_bounds__(256) void k4_final(
    const float* __restrict__ X, const float* __restrict__ lw,
    float* __restrict__ out, int nnodes)
{
    __shared__ float ps[4][64][12];
    const int tid = threadIdx.x;
    const int n0 = blockIdx.x * 4;
    if (n0 >= nnodes) return;
    const float* src = out + (size_t)n0 * 576;   // pc, comp-major [node][9][64]
    for (int i = tid; i < 2304; i += 256) {
        int sub = i / 576; int rem = i - sub * 576;
        int c = rem >> 6; int hh = rem & 63;
        ps[sub][hh][c] = src[i];
    }
    __syncthreads();

    const int sub = tid >> 6, g = tid & 63;
    const float* W3 = lw + 3 * 4096 + g * 64;
    const float* W4 = lw + 4 * 4096 + g * 64;
    const float* W5 = lw + 5 * 4096 + g * 64;
    float acc[9];
#pragma unroll
    for (int i = 0; i < 9; i++) acc[i] = 0.f;
#pragma unroll 4
    for (int h = 0; h < 64; ++h) {
        float w3v = W3[h], w4v = W4[h], w5v = W5[h];
        const float* ic = ps[sub][h];
        acc[0] = fmaf(w3v, ic[0], acc[0]);
        acc[1] = fmaf(w4v, ic[1], acc[1]);
        acc[2] = fmaf(w4v, ic[2], acc[2]);
        acc[3] = fmaf(w4v, ic[3], acc[3]);
        acc[4] = fmaf(w5v, ic[4], acc[4]);
        acc[5] = fmaf(w5v, ic[5], acc[5]);
        acc[6] = fmaf(w5v, ic[6], acc[6]);
        acc[7] = fmaf(w5v, ic[7], acc[7]);
        acc[8] = fmaf(w5v, ic[8], acc[8]);
    }
    float D[9];
    D[0] = acc[0] + acc[4]; D[1] = acc[1] + acc[5]; D[2] = acc[2] + acc[6];
    D[3] = -acc[1] + acc[5]; D[4] = acc[0] + acc[7]; D[5] = acc[3] + acc[8];
    D[6] = -acc[2] + acc[6]; D[7] = -acc[3] + acc[8]; D[8] = acc[0] - acc[4] - acc[7];

    const float* xp = X + ((size_t)(n0 + sub) * 64 + g) * 9;
    float xv[9];
#pragma unroll
    for (int i = 0; i < 9; i++) xv[i] = xp[i];
    float tn = 0.f;
#pragma unroll
    for (int i = 0; i < 9; i++) tn = fmaf(xv[i], xv[i], tn);
    float inv = 1.0f / (tn + 1.0f);

    float* op = out + ((size_t)(n0 + sub) * 64 + g) * 9;   // final output, [N][64][3][3]
    float res[9];
#pragma unroll
    for (int a = 0; a < 3; a++)
#pragma unroll
        for (int b = 0; b < 3; b++) {
            float dd = 0.f;
#pragma unroll
            for (int c = 0; c < 3; c++) dd = fmaf(D[a * 3 + c], D[c * 3 + b], dd);
            res[a * 3 + b] = xv[a * 3 + b] * inv + D[a * 3 + b] + dd;
        }
    __syncthreads();   // all reads of pc staged before overwrite
#pragma unroll
    for (int i = 0; i < 9; i++) op[i] = res[i];
}

extern "C" void kernel_launch(void* const* d_in, const int* in_sizes, int n_in,
                              void* d_out, int out_size, void* d_ws, size_t ws_size,
                              hipStream_t stream)
{
    const float* X    = (const float*)d_in[0];
    const int*   eidx = (const int*)d_in[1];
    const float* dist = (const float*)d_in[2];
    const float* ea   = (const float*)d_in[3];
    const float* w1   = (const float*)d_in[4];
    const float* b1   = (const float*)d_in[5];
    const float* w2   = (const float*)d_in[6];
    const float* b2   = (const float*)d_in[7];
    const float* w3   = (const float*)d_in[8];
    const float* b3   = (const float*)d_in[9];
    const float* lw   = (const float*)d_in[10];
    float* outp = (float*)d_out;

    const int nnodes = in_sizes[0] / (64 * 9);   // 20000
    const int nedges = in_sizes[2];              // 320000

    float* Tm   = (float*)d_ws;                          // N*576 f32
    __half* efs = (__half*)(Tm + (size_t)nnodes * 576);  // E*192 f16, layout [pos][3h+c]
    int* cur    = (int*)(efs + (size_t)nedges * 192);
    int* off    = cur + nnodes;                          // nnodes+1
    int* perm   = off + nnodes + 1;                      // nedges
    int* col_s  = perm + nedges;                         // nedges

    // CSR build (edges sorted by destination row; col pre-gathered)
    hipMemsetAsync(cur, 0, (size_t)nnodes * sizeof(int), stream);
    k_hist<<<(nedges + 255) / 256, 256, 0, stream>>>(eidx, cur, nedges);
    k_scan2<<<1, 1024, 0, stream>>>(cur, off, nnodes);
    k_scatter<<<(nedges + 255) / 256, 256, 0, stream>>>(eidx, cur, perm, col_s, nedges);

    k1_node_mix<<<(nnodes + 3) / 4, 256, 0, stream>>>(X, lw, Tm, nnodes);
    k2a_mfma<<<(nedges + 511) / 512, 512, 0, stream>>>(ea, dist, perm, w1, b1, w2, b2, w3, b3, efs, nedges);
    k2b_acc<<<(nnodes + 3) / 4, 256, 0, stream>>>(Tm, efs, col_s, off, outp, nnodes);
    k4_final<<<(nnodes + 3) / 4, 256, 0, stream>>>(X, lw, outp, nnodes);
}

// Round 6
// 493.848 us; speedup vs baseline: 12.6925x; 1.2203x over previous
//
#include <hip/hip_runtime.h>
#include <hip/hip_fp16.h>

#define NR 32

typedef __attribute__((ext_vector_type(8))) short bf8_t;   // 8 x bf16 (4 VGPR)
typedef __attribute__((ext_vector_type(4))) float f4_t;

__device__ __forceinline__ float silu_f(float x) { return x / (1.0f + __expf(-x)); }

__device__ __forceinline__ unsigned short f2bf(float x) {
    unsigned u = __float_as_uint(x);
    u += 0x7FFF + ((u >> 16) & 1);          // round-to-nearest-even
    return (unsigned short)(u >> 16);
}

__device__ __forceinline__ float rdl(float v, int l) {
    return __int_as_float(__builtin_amdgcn_readlane(__float_as_int(v), l));
}

// ---------------- CSR build ----------------
__global__ __launch_bounds__(256) void k_hist(
    const int* __restrict__ eidx, int* __restrict__ cnt, int nedges)
{
    int e = blockIdx.x * 256 + threadIdx.x;
    if (e < nedges) atomicAdd(&cnt[eidx[e]], 1);
}

__global__ __launch_bounds__(1024) void k_scan2(
    int* __restrict__ cnt, int* __restrict__ off, int n)
{
    __shared__ int wsum[16];
    __shared__ int wbase[16];
    const int tid = threadIdx.x;
    const int lane = tid & 63, wid = tid >> 6;
    const int per = (n + 1023) >> 10;
    const int base = tid * per;
    int s = 0;
    for (int i = 0; i < per; i++) {
        int idx = base + i;
        if (idx < n) s += cnt[idx];
    }
    int incl = s;
    for (int d = 1; d < 64; d <<= 1) {
        int t = __shfl_up(incl, d);
        if (lane >= d) incl += t;
    }
    if (lane == 63) wsum[wid] = incl;
    __syncthreads();
    if (wid == 0) {
        int v = (lane < 16) ? wsum[lane] : 0;
        int inc2 = v;
        for (int d = 1; d < 16; d <<= 1) {
            int t = __shfl_up(inc2, d);
            if (lane >= d) inc2 += t;
        }
        if (lane < 16) wbase[lane] = inc2 - v;
        if (lane == 15) off[n] = inc2;
    }
    __syncthreads();
    int run = wbase[wid] + incl - s;
    for (int i = 0; i < per; i++) {
        int idx = base + i;
        if (idx < n) {
            int v = cnt[idx];
            off[idx] = run;
            cnt[idx] = run;
            run += v;
        }
    }
}

__global__ __launch_bounds__(256) void k_scatter(
    const int* __restrict__ eidx, int* __restrict__ cur,
    int* __restrict__ perm, int* __restrict__ col_s, int nedges)
{
    int e = blockIdx.x * 256 + threadIdx.x;
    if (e < nedges) {
        int r = eidx[e];
        int pos = atomicAdd(&cur[r], 1);
        perm[pos] = e;
        col_s[pos] = eidx[nedges + e];
    }
}

// ---------------- K1: node decompose + mix (lin_w[0..2]) -> Tm[N][9][64] comp-major ----------------
// wave = one node; lane = h for decompose, lane = g for mix; values broadcast via v_readlane.
__global__ __launch_bounds__(512) void k1_node_mix(
    const float* __restrict__ X, const float* __restrict__ lw,
    float* __restrict__ Tm, int nnodes)
{
    __shared__ float Wl[3 * 64 * 68];      // padded rows (68 dwords, 16B-aligned)
    const int tid = threadIdx.x;
#pragma unroll
    for (int k = 0; k < 6; k++) {          // stage lw[0..2]: 12288 floats coalesced
        int l = (tid + k * 512) * 4;
        int row = l >> 6, col = l & 63;
        *(float4*)&Wl[row * 68 + col] = *(const float4*)(lw + l);
    }

    const int wid = tid >> 6, lane = tid & 63;
    const int n = blockIdx.x * 8 + wid;
    const bool valid = (n < nnodes);

    float i0 = 0, i1 = 0, i2 = 0, i3 = 0, i4 = 0, i5 = 0, i6 = 0, i7 = 0, i8 = 0;
    if (valid) {
        const float* xp = X + ((size_t)n * 64 + lane) * 9;
        float v[9];
#pragma unroll
        for (int i = 0; i < 9; i++) v[i] = xp[i];
        float tn = 0.f;
#pragma unroll
        for (int i = 0; i < 9; i++) tn = fmaf(v[i], v[i], tn);
        float inv = 1.0f / (tn + 1.0f);
#pragma unroll
        for (int i = 0; i < 9; i++) v[i] *= inv;
        float lam = (v[0] + v[4] + v[8]) * (1.0f / 3.0f);
        i0 = lam;
        i1 = (v[1] - v[3]) * 0.5f;
        i2 = (v[2] - v[6]) * 0.5f;
        i3 = (v[5] - v[7]) * 0.5f;
        i4 = v[0] - lam;
        i5 = (v[1] + v[3]) * 0.5f;
        i6 = (v[2] + v[6]) * 0.5f;
        i7 = v[4] - lam;
        i8 = (v[5] + v[7]) * 0.5f;
    }
    __syncthreads();

    const int g = lane;
    float a0 = 0, a1 = 0, a2 = 0, a3 = 0, a4 = 0, a5 = 0, a6 = 0, a7 = 0, a8 = 0;
#pragma unroll
    for (int h4 = 0; h4 < 64; h4 += 4) {
        float4 w0 = *(const float4*)&Wl[g * 68 + h4];
        float4 w1 = *(const float4*)&Wl[(64 + g) * 68 + h4];
        float4 w2 = *(const float4*)&Wl[(128 + g) * 68 + h4];
#pragma unroll
        for (int j = 0; j < 4; j++) {
            const int h = h4 + j;
            float wa = (&w0.x)[j], wb = (&w1.x)[j], wc = (&w2.x)[j];
            a0 = fmaf(wa, rdl(i0, h), a0);
            a1 = fmaf(wb, rdl(i1, h), a1);
            a2 = fmaf(wb, rdl(i2, h), a2);
            a3 = fmaf(wb, rdl(i3, h), a3);
            a4 = fmaf(wc, rdl(i4, h), a4);
            a5 = fmaf(wc, rdl(i5, h), a5);
            a6 = fmaf(wc, rdl(i6, h), a6);
            a7 = fmaf(wc, rdl(i7, h), a7);
            a8 = fmaf(wc, rdl(i8, h), a8);
        }
    }
    if (valid) {
        float* outp = Tm + (size_t)n * 576 + g;
        outp[0 * 64] = a0; outp[1 * 64] = a1; outp[2 * 64] = a2;
        outp[3 * 64] = a3; outp[4 * 64] = a4; outp[5 * 64] = a5;
        outp[6 * 64] = a6; outp[7 * 64] = a7; outp[8 * 64] = a8;
    }
}

// ---------------- K2a: MFMA fused edge MLP -> efs[pos][192] fp16 (f = 3h+c) ----------------
// LDS map (bytes): w1 [0,4096) linear; w2 [4096,20480) swz; w3 [20480,69632) swz;
// per-wave act: h1 (2 KB bf16 [16][64]) + h2 (4 KB bf16 [16][128]) at 69632 + wid*6144.
#define LW1 0
#define LW2 4096
#define LW3 20480
#define LHB 69632

__global__ __launch_bounds__(512) void k2a_mfma(
    const float* __restrict__ ea, const float* __restrict__ dist,
    const int* __restrict__ perm,
    const float* __restrict__ w1, const float* __restrict__ b1,
    const float* __restrict__ w2, const float* __restrict__ b2,
    const float* __restrict__ w3, const float* __restrict__ b3,
    __half* __restrict__ efs, int nedges)
{
    __shared__ __align__(16) char smem[118784];
    const int tid = threadIdx.x;

    // ---- stage weights as bf16 (block-wide, once) ----
    for (int i = tid; i < 1024; i += 512) {            // w1: 64x32, linear rows (64 B row)
        unsigned lo = f2bf(w1[2 * i]), hi = f2bf(w1[2 * i + 1]);
        *(unsigned*)(smem + LW1 + i * 4) = lo | (hi << 16);
    }
    for (int i = tid; i < 4096; i += 512) {            // w2: 128x64, 128 B row, swz
        int row = i >> 5, pc = i & 31;
        int byte = (row * 128 + pc * 4) ^ ((row & 7) << 4);
        unsigned lo = f2bf(w2[2 * i]), hi = f2bf(w2[2 * i + 1]);
        *(unsigned*)(smem + LW2 + byte) = lo | (hi << 16);
    }
    for (int i = tid; i < 12288; i += 512) {           // w3: 192x128, 256 B row, swz
        int row = i >> 6, pc = i & 63;
        int byte = (row * 256 + pc * 4) ^ ((row & 7) << 4);
        unsigned lo = f2bf(w3[2 * i]), hi = f2bf(w3[2 * i + 1]);
        *(unsigned*)(smem + LW3 + byte) = lo | (hi << 16);
    }
    __syncthreads();

    const int wid = tid >> 6, lane = tid & 63;
    const int r = lane & 15, g = lane >> 4;
    char* h1b = smem + LHB + wid * 6144;
    char* h2b = h1b + 2048;
    const int eb = blockIdx.x * 512 + wid * 64;
    if (eb >= nedges) return;

    // held B-frags for w1 (K=32 fits one frag set)
    bf8_t bw1[4];
#pragma unroll
    for (int nt = 0; nt < 4; nt++)
        bw1[nt] = *(const bf8_t*)(smem + LW1 + (16 * nt + r) * 64 + g * 16);

    float b1v[4], b2v[8], b3v[12];
#pragma unroll
    for (int nt = 0; nt < 4; nt++)  b1v[nt] = b1[16 * nt + r];
#pragma unroll
    for (int nt = 0; nt < 8; nt++)  b2v[nt] = b2[16 * nt + r];
#pragma unroll
    for (int nt = 0; nt < 12; nt++) b3v[nt] = b3[16 * nt + r];

    for (int mt = 0; mt < 4; mt++) {
        int p = eb + mt * 16 + r;
        int pcl = min(p, nedges - 1);
        int e = perm[pcl];

        // A1 frag: ea[e][8g..8g+7] (row=r edge, k contiguous)
        const float* ar = ea + (size_t)e * NR + 8 * g;
        float4 v0 = *(const float4*)(ar);
        float4 v1 = *(const float4*)(ar + 4);
        bf8_t a1;
        a1[0] = f2bf(v0.x); a1[1] = f2bf(v0.y); a1[2] = f2bf(v0.z); a1[3] = f2bf(v0.w);
        a1[4] = f2bf(v1.x); a1[5] = f2bf(v1.y); a1[6] = f2bf(v1.z); a1[7] = f2bf(v1.w);

        float d = dist[e];
        float cf = (d < 5.0f) ? 0.5f * (__cosf(d * 0.62831853071795864f) + 1.0f) : 0.0f;
        float cfr[4];
#pragma unroll
        for (int j = 0; j < 4; j++) cfr[j] = __shfl(cf, 4 * g + j);   // cf of C-row 4g+j

        // ---- L1: h1[16][64] ----
#pragma unroll
        for (int nt = 0; nt < 4; nt++) {
            f4_t c = { b1v[nt], b1v[nt], b1v[nt], b1v[nt] };
            c = __builtin_amdgcn_mfma_f32_16x16x32_bf16(a1, bw1[nt], c, 0, 0, 0);
#pragma unroll
            for (int j = 0; j < 4; j++) {
                int row = 4 * g + j, col = 16 * nt + r;
                int byte = (row * 128 + col * 2) ^ ((row & 7) << 4);
                *(unsigned short*)(h1b + byte) = f2bf(silu_f(c[j]));
            }
        }

        // ---- L2: h2[16][128] ----
        bf8_t a2[2];
#pragma unroll
        for (int kt = 0; kt < 2; kt++)
            a2[kt] = *(const bf8_t*)(h1b + ((r * 128 + kt * 64 + g * 16) ^ ((r & 7) << 4)));
#pragma unroll
        for (int nt = 0; nt < 8; nt++) {
            int c0 = 16 * nt + r;
            f4_t c = { b2v[nt], b2v[nt], b2v[nt], b2v[nt] };
#pragma unroll
            for (int kt = 0; kt < 2; kt++) {
                bf8_t bw = *(const bf8_t*)(smem + LW2 + ((c0 * 128 + kt * 64 + g * 16) ^ ((c0 & 7) << 4)));
                c = __builtin_amdgcn_mfma_f32_16x16x32_bf16(a2[kt], bw, c, 0, 0, 0);
            }
#pragma unroll
            for (int j = 0; j < 4; j++) {
                int row = 4 * g + j;
                int byte = (row * 256 + (16 * nt + r) * 2) ^ ((row & 7) << 4);
                *(unsigned short*)(h2b + byte) = f2bf(silu_f(c[j]));
            }
        }

        // ---- L3: [16][192] + cutoff epilogue ----
        bf8_t a3[4];
#pragma unroll
        for (int kt = 0; kt < 4; kt++)
            a3[kt] = *(const bf8_t*)(h2b + ((r * 256 + kt * 64 + g * 16) ^ ((r & 7) << 4)));
#pragma unroll
        for (int nt = 0; nt < 12; nt++) {
            int c0 = 16 * nt + r;
            f4_t c = { b3v[nt], b3v[nt], b3v[nt], b3v[nt] };
#pragma unroll
            for (int kt = 0; kt < 4; kt++) {
                bf8_t bw = *(const bf8_t*)(smem + LW3 + ((c0 * 256 + kt * 64 + g * 16) ^ ((c0 & 7) << 4)));
                c = __builtin_amdgcn_mfma_f32_16x16x32_bf16(a3[kt], bw, c, 0, 0, 0);
            }
#pragma unroll
            for (int j = 0; j < 4; j++) {
                int prow = eb + mt * 16 + 4 * g + j;
                if (prow < nedges)
                    efs[(size_t)prow * 192 + 16 * nt + r] = __float2half(c[j] * cfr[j]);
            }
        }
    }
}

// ---------------- K2b: row-per-wave accumulate + fused k3 -> out (pc, comp-major) ----------------
__global__ __launch_bounds__(256) void k2b_acc(
    const float* __restrict__ Tm, const __half* __restrict__ efs,
    const int* __restrict__ col_s, const int* __restrict__ off,
    float* __restrict__ out, int nrows)
{
    const int wid = threadIdx.x >> 6, lane = threadIdx.x & 63;
    const int r = blockIdx.x * 4 + wid;
    if (r >= nrows) return;
    const int beg = off[r];
    const int end = off[r + 1];

    float acc[9];
#pragma unroll
    for (int i = 0; i < 9; i++) acc[i] = 0.f;

#pragma unroll 2
    for (int p = beg; p < end; ++p) {
        int col = col_s[p];
        const float* t = Tm + (size_t)col * 576 + lane;
        const __half* f = efs + (size_t)p * 192 + 3 * lane;
        float f0 = __half2float(f[0]);
        float f1 = __half2float(f[1]);
        float f2 = __half2float(f[2]);
        acc[0] = fmaf(f0, t[0 * 64], acc[0]);
        acc[1] = fmaf(f1, t[1 * 64], acc[1]);
        acc[2] = fmaf(f1, t[2 * 64], acc[2]);
        acc[3] = fmaf(f1, t[3 * 64], acc[3]);
        acc[4] = fmaf(f2, t[4 * 64], acc[4]);
        acc[5] = fmaf(f2, t[5 * 64], acc[5]);
        acc[6] = fmaf(f2, t[6 * 64], acc[6]);
        acc[7] = fmaf(f2, t[7 * 64], acc[7]);
        acc[8] = fmaf(f2, t[8 * 64], acc[8]);
    }

    // fused k3: prod = M@Y + Y@M, decompose, /norm
    float y[9];
    {
        const float* tp = Tm + (size_t)r * 576 + lane;
#pragma unroll
        for (int k = 0; k < 9; k++) y[k] = tp[k * 64];
    }
    float Y[9], Mm[9];
    Y[0] = y[0] + y[4]; Y[1] = y[1] + y[5]; Y[2] = y[2] + y[6];
    Y[3] = -y[1] + y[5]; Y[4] = y[0] + y[7]; Y[5] = y[3] + y[8];
    Y[6] = -y[2] + y[6]; Y[7] = -y[3] + y[8]; Y[8] = y[0] - y[4] - y[7];
    Mm[0] = acc[0] + acc[4]; Mm[1] = acc[1] + acc[5]; Mm[2] = acc[2] + acc[6];
    Mm[3] = -acc[1] + acc[5]; Mm[4] = acc[0] + acc[7]; Mm[5] = acc[3] + acc[8];
    Mm[6] = -acc[2] + acc[6]; Mm[7] = -acc[3] + acc[8]; Mm[8] = acc[0] - acc[4] - acc[7];
    float P[9];
#pragma unroll
    for (int a = 0; a < 3; a++)
#pragma unroll
        for (int b = 0; b < 3; b++) {
            float s = 0.f;
#pragma unroll
            for (int c = 0; c < 3; c++) {
                s = fmaf(Mm[a * 3 + c], Y[c * 3 + b], s);
                s = fmaf(Y[a * 3 + c], Mm[c * 3 + b], s);
            }
            P[a * 3 + b] = s;
        }
    float tn = 0.f;
#pragma unroll
    for (int k = 0; k < 9; k++) tn = fmaf(P[k], P[k], tn);
    float inv = 1.0f / (tn + 1.0f);
    float lam = (P[0] + P[4] + P[8]) * (1.0f / 3.0f);

    float* mp = out + (size_t)r * 576 + lane;
    mp[0 * 64] = lam * inv;
    mp[1 * 64] = (P[1] - P[3]) * 0.5f * inv;
    mp[2 * 64] = (P[2] - P[6]) * 0.5f * inv;
    mp[3 * 64] = (P[5] - P[7]) * 0.5f * inv;
    mp[4 * 64] = (P[0] - lam) * inv;
    mp[5 * 64] = (P[1] + P[3]) * 0.5f * inv;
    mp[6 * 64] = (P[2] + P[6]) * 0.5f * inv;
    mp[7 * 64] = (P[4] - lam) * inv;
    mp[8 * 64] = (P[5] + P[7]) * 0.5f * inv;
}

// ---------------- K4: mix (lin_w[3..5]) -> dX; out = Xn + dX + dX@dX (in-place over pc) ----------------
// wave = one node; values from pc (comp-major) per-lane, broadcast via v_readlane.
__global__ __launch_bounds__(512) void k4_final(
    const float* __restrict__ X, const float* __restrict__ lw,
    float* __restrict__ out, int nnodes)
{
    __shared__ float Wl[3 * 64 * 68];
    const int tid = threadIdx.x;
#pragma unroll
    for (int k = 0; k < 6; k++) {          // stage lw[3..5]
        int l = (tid + k * 512) * 4;
        int row = l >> 6, col = l & 63;
        *(float4*)&Wl[row * 68 + col] = *(const float4*)(lw + 3 * 4096 + l);
    }

    const int wid = tid >> 6, lane = tid & 63;
    const int n = blockIdx.x * 8 + wid;
    const bool valid = (n < nnodes);

    float i0 = 0, i1 = 0, i2 = 0, i3 = 0, i4 = 0, i5 = 0, i6 = 0, i7 = 0, i8 = 0;
    if (valid) {
        const float* pp = out + (size_t)n * 576 + lane;   // pc comp-major [n][9][64]
        i0 = pp[0 * 64]; i1 = pp[1 * 64]; i2 = pp[2 * 64];
        i3 = pp[3 * 64]; i4 = pp[4 * 64]; i5 = pp[5 * 64];
        i6 = pp[6 * 64]; i7 = pp[7 * 64]; i8 = pp[8 * 64];
    }
    __syncthreads();

    const int g = lane;
    float a0 = 0, a1 = 0, a2 = 0, a3 = 0, a4 = 0, a5 = 0, a6 = 0, a7 = 0, a8 = 0;
#pragma unroll
    for (int h4 = 0; h4 < 64; h4 += 4) {
        float4 w0 = *(const float4*)&Wl[g * 68 + h4];
        float4 w1 = *(const float4*)&Wl[(64 + g) * 68 + h4];
        float4 w2 = *(const float4*)&Wl[(128 + g) * 68 + h4];
#pragma unroll
        for (int j = 0; j < 4; j++) {
            const int h = h4 + j;
            float wa = (&w0.x)[j], wb = (&w1.x)[j], wc = (&w2.x)[j];
            a0 = fmaf(wa, rdl(i0, h), a0);
            a1 = fmaf(wb, rdl(i1, h), a1);
            a2 = fmaf(wb, rdl(i2, h), a2);
            a3 = fmaf(wb, rdl(i3, h), a3);
            a4 = fmaf(wc, rdl(i4, h), a4);
            a5 = fmaf(wc, rdl(i5, h), a5);
            a6 = fmaf(wc, rdl(i6, h), a6);
            a7 = fmaf(wc, rdl(i7, h), a7);
            a8 = fmaf(wc, rdl(i8, h), a8);
        }
    }

    if (valid) {
        float D[9];
        D[0] = a0 + a4; D[1] = a1 + a5; D[2] = a2 + a6;
        D[3] = -a1 + a5; D[4] = a0 + a7; D[5] = a3 + a8;
        D[6] = -a2 + a6; D[7] = -a3 + a8; D[8] = a0 - a4 - a7;

        const float* xp = X + ((size_t)n * 64 + g) * 9;
        float xv[9];
#pragma unroll
        for (int i = 0; i < 9; i++) xv[i] = xp[i];
        float tn = 0.f;
#pragma unroll
        for (int i = 0; i < 9; i++) tn = fmaf(xv[i], xv[i], tn);
        float inv = 1.0f / (tn + 1.0f);

        float* op = out + ((size_t)n * 64 + g) * 9;   // final [N][64][3][3]
        float res[9];
#pragma unroll
        for (int a = 0; a < 3; a++)
#pragma unroll
            for (int b = 0; b < 3; b++) {
                float dd = 0.f;
#pragma unroll
                for (int c = 0; c < 3; c++) dd = fmaf(D[a * 3 + c], D[c * 3 + b], dd);
                res[a * 3 + b] = xv[a * 3 + b] * inv + D[a * 3 + b] + dd;
            }
#pragma unroll
        for (int i = 0; i < 9; i++) op[i] = res[i];
    }
}

extern "C" void kernel_launch(void* const* d_in, const int* in_sizes, int n_in,
                              void* d_out, int out_size, void* d_ws, size_t ws_size,
                              hipStream_t stream)
{
    const float* X    = (const float*)d_in[0];
    const int*   eidx = (const int*)d_in[1];
    const float* dist = (const float*)d_in[2];
    const float* ea   = (const float*)d_in[3];
    const float* w1   = (const float*)d_in[4];
    const float* b1   = (const float*)d_in[5];
    const float* w2   = (const float*)d_in[6];
    const float* b2   = (const float*)d_in[7];
    const float* w3   = (const float*)d_in[8];
    const float* b3   = (const float*)d_in[9];
    const float* lw   = (const float*)d_in[10];
    float* outp = (float*)d_out;

    const int nnodes = in_sizes[0] / (64 * 9);   // 20000
    const int nedges = in_sizes[2];              // 320000

    float* Tm   = (float*)d_ws;                          // N*576 f32
    __half* efs = (__half*)(Tm + (size_t)nnodes * 576);  // E*192 f16, layout [pos][3h+c]
    int* cur    = (int*)(efs + (size_t)nedges * 192);
    int* off    = cur + nnodes;                          // nnodes+1
    int* perm   = off + nnodes + 1;                      // nedges
    int* col_s  = perm + nedges;                         // nedges

    // CSR build (edges sorted by destination row; col pre-gathered)
    hipMemsetAsync(cur, 0, (size_t)nnodes * sizeof(int), stream);
    k_hist<<<(nedges + 255) / 256, 256, 0, stream>>>(eidx, cur, nedges);
    k_scan2<<<1, 1024, 0, stream>>>(cur, off, nnodes);
    k_scatter<<<(nedges + 255) / 256, 256, 0, stream>>>(eidx, cur, perm, col_s, nedges);

    k1_node_mix<<<(nnodes + 7) / 8, 512, 0, stream>>>(X, lw, Tm, nnodes);
    k2a_mfma<<<(nedges + 511) / 512, 512, 0, stream>>>(ea, dist, perm, w1, b1, w2, b2, w3, b3, efs, nedges);
    k2b_acc<<<(nnodes + 3) / 4, 256, 0, stream>>>(Tm, efs, col_s, off, outp, nnodes);
    k4_final<<<(nnodes + 7) / 8, 512, 0, stream>>>(X, lw, outp, nnodes);
}